// Round 15
// baseline (1831.025 us; speedup 1.0000x reference)
//
#include <hip/hip_runtime.h>
#include <math.h>

constexpr int NB = 32, NN = 1024, KNN = 20;
constexpr int RTOT = NB * NN; // 32768

// ---------------- workspace offsets (in floats) ----------------
constexpr size_t SZ_BIG = (size_t)NB * NN * 40 * 64;      // 83,886,080 (u_hat / D / Z / fcat / ybufs)
constexpr size_t O_BIG  = 0;
constexpr size_t O_XT0  = O_BIG + SZ_BIG;                  // (B,N,4) data transposed
constexpr size_t O_XT1  = O_XT0 + (size_t)RTOT * 4;        // (B,N,64)
constexpr size_t O_XT2  = O_XT1 + (size_t)RTOT * 64;       // (B,N,64)
constexpr size_t O_XT3  = O_XT2 + (size_t)RTOT * 64;       // (B,N,128)
constexpr size_t O_XX   = O_XT3 + (size_t)RTOT * 128;      // row norms
constexpr size_t O_IDX  = O_XX + RTOT;                     // int (B,N,20)
constexpr size_t O_WC1  = O_IDX + (size_t)RTOT * KNN;      // 4x128
constexpr size_t O_WC2  = O_WC1 + 512;                     // 64x128
constexpr size_t O_WC3  = O_WC2 + 8192;                    // 64x256
constexpr size_t O_LWT  = O_WC3 + 16384;                   // 256x64
constexpr size_t O_C2T  = O_LWT + 16384;                   // 40x256
constexpr size_t O_C3T  = O_C2T + 10240;                   // 256x256
constexpr size_t O_C4T  = O_C3T + 65536;                   // 256x128
constexpr size_t O_C5T  = O_C4T + 32768;                   // 128x64
constexpr size_t O_H    = O_C5T + 8192;                    // (B,N,64) h / encoder
constexpr size_t O_LNST = O_H + (size_t)RTOT * 64;         // 2 per b
constexpr size_t O_BSUM = O_LNST + 64;
constexpr size_t O_BSQ  = O_BSUM + 256;
constexpr size_t O_SCL  = O_BSQ + 256;
constexpr size_t O_SHF  = O_SCL + 256;
constexpr size_t O_SACC = O_SHF + 256;                     // (B,40,64) (unused now)
constexpr size_t O_VB   = O_SACC + 81920;                  // (B,40,64)
constexpr size_t O_BIJ  = O_VB + 81920;                    // (B,40,1024) routing b; ALSO partials
constexpr size_t O_EMB  = O_BIJ + (size_t)NB * 40 * NN;    // (B,N)
constexpr size_t O_LAB  = O_EMB + RTOT;                    // (B,64) (unused now)
constexpr size_t O_BASE = O_LAB + 2048;                    // (B,256)
// BN partials alias bij (lifetimes disjoint)
constexpr size_t O_PS   = O_BIJ;                           // 128 * 2048 (stage BN) / 256*128 (conv BN)
constexpr size_t O_PQ   = O_BIJ + 262144;
// partial buffers alias xt1..xt3 (dead after k_concat):
constexpr size_t O_PB   = O_XT1;   // routing partials: 32*81920 floats
constexpr size_t O_PBU  = O_XT1;   // uhat s-sum partials: 64*81920 floats

__device__ __forceinline__ float lrelu(float z) { return fmaxf(z, 0.2f * z); }

// sortable-uint key <-> float (ascending key == ascending float)
__device__ __forceinline__ float key2f(unsigned u)
{
    unsigned b = (u & 0x80000000u) ? (u ^ 0x80000000u) : ~u;
    return __uint_as_float(b);
}

// ---------- all weight transposes in ONE kernel (blockIdx-range dispatch)
__device__ __forceinline__ void wt_do(const float* __restrict__ src, float* __restrict__ dst,
                                      int i, int K, int On, int SS, int coff, int DS, int ooff, int Oreal)
{
    if (i >= K * On) return;
    int c = i / On, o = i - c * On;
    dst[(size_t)c * DS + ooff + o] = (o < Oreal) ? src[(size_t)o * SS + coff + c] : 0.f;
}

__global__ __launch_bounds__(256) void k_wtall(
    const float* __restrict__ dw1, const float* __restrict__ dw2, const float* __restrict__ dw3,
    const float* __restrict__ lw,  const float* __restrict__ cw2, const float* __restrict__ cw3,
    const float* __restrict__ cw4, const float* __restrict__ cw5,
    float* __restrict__ wc1, float* __restrict__ wc2, float* __restrict__ wc3,
    float* __restrict__ lwt, float* __restrict__ c2t, float* __restrict__ c3t,
    float* __restrict__ c4t, float* __restrict__ c5t)
{
    int bid = blockIdx.x, t = threadIdx.x;
    if      (bid < 1)   wt_do(dw1, wc1, (bid - 0) * 256 + t,   3, 64, 6, 0, 128, 0, 64);
    else if (bid < 2)   wt_do(dw1, wc1, (bid - 1) * 256 + t,   3, 64, 6, 3, 128, 64, 64);
    else if (bid < 18)  wt_do(dw2, wc2, (bid - 2) * 256 + t,   64, 64, 128, 0, 128, 0, 64);
    else if (bid < 34)  wt_do(dw2, wc2, (bid - 18) * 256 + t,  64, 64, 128, 64, 128, 64, 64);
    else if (bid < 66)  wt_do(dw3, wc3, (bid - 34) * 256 + t,  64, 128, 128, 0, 256, 0, 128);
    else if (bid < 98)  wt_do(dw3, wc3, (bid - 66) * 256 + t,  64, 128, 128, 64, 256, 128, 128);
    else if (bid < 162) wt_do(lw,  lwt, (bid - 98) * 256 + t,  256, 64, 256, 0, 64, 0, 40);
    else if (bid < 202) wt_do(cw2, c2t, (bid - 162) * 256 + t, 40, 256, 1128, 1088, 256, 0, 256);
    else if (bid < 458) wt_do(cw3, c3t, (bid - 202) * 256 + t, 256, 256, 256, 0, 256, 0, 256);
    else if (bid < 586) wt_do(cw4, c4t, (bid - 458) * 256 + t, 256, 128, 256, 0, 128, 0, 128);
    else                wt_do(cw5, c5t, (bid - 586) * 256 + t, 128, 64, 128, 0, 64, 0, 50);
}

// ---------- data (B,3,N) -> xt0 (B,N,4), fused row-norm
__global__ void k_data_t(const float* __restrict__ d, float* __restrict__ xt,
                         float* __restrict__ xx)
{
    int i = blockIdx.x * 256 + threadIdx.x;
    if (i >= RTOT) return;
    int b = i >> 10, n = i & 1023;
    float s = 0.f;
#pragma unroll
    for (int c = 0; c < 3; ++c) {
        float v = d[((size_t)b * 3 + c) * NN + n];
        xt[(size_t)i * 4 + c] = v;
        s = fmaf(v, v, s);
    }
    xt[(size_t)i * 4 + 3] = 0.f;
    xx[i] = s;
}

// ---------- batched pairwise-score GEMM: D[b,r,m] = 2 * x_r . x_m - ||x_m||^2
// Staging via guarded float4 loads (XS%4==0, kb%4==0 -> in-row 16B).
template<int CS>
__global__ __launch_bounds__(256) void k_dist(const float* __restrict__ X,
    const float* __restrict__ xx, float* __restrict__ D)
{
    __shared__ float As[16][68];
    __shared__ float Bs[16][68];
    int b = blockIdx.z;
    int r0 = blockIdx.x * 64, m0 = blockIdx.y * 64;
    const float* Xb = X + (size_t)b * NN * CS;
    int t = threadIdx.x;
    int tx = t & 15, ty = t >> 4;
    float acc[4][4] = {};
    for (int k0 = 0; k0 < CS; k0 += 16) {
        __syncthreads();
        {
            int row = t >> 2, kb = (t & 3) * 4;
            float4 a4 = make_float4(0.f, 0.f, 0.f, 0.f);
            float4 b4 = make_float4(0.f, 0.f, 0.f, 0.f);
            if (k0 + kb < CS) {
                a4 = *(const float4*)&Xb[(size_t)(r0 + row) * CS + k0 + kb];
                b4 = *(const float4*)&Xb[(size_t)(m0 + row) * CS + k0 + kb];
            }
            As[kb + 0][row] = a4.x; As[kb + 1][row] = a4.y;
            As[kb + 2][row] = a4.z; As[kb + 3][row] = a4.w;
            Bs[kb + 0][row] = b4.x; Bs[kb + 1][row] = b4.y;
            Bs[kb + 2][row] = b4.z; Bs[kb + 3][row] = b4.w;
        }
        __syncthreads();
#pragma unroll
        for (int k = 0; k < 16; ++k) {
            float4 a = *(const float4*)&As[k][ty * 4];
            float4 bb = *(const float4*)&Bs[k][tx * 4];
            float av[4] = {a.x, a.y, a.z, a.w};
            float bv[4] = {bb.x, bb.y, bb.z, bb.w};
#pragma unroll
            for (int i = 0; i < 4; ++i)
#pragma unroll
                for (int j = 0; j < 4; ++j)
                    acc[i][j] = fmaf(av[i], bv[j], acc[i][j]);
        }
    }
    const float* xxb = xx + b * NN + m0 + tx * 4;
    float x0 = xxb[0], x1 = xxb[1], x2 = xxb[2], x3 = xxb[3];
#pragma unroll
    for (int i = 0; i < 4; ++i) {
        float4 o4 = make_float4(2.f * acc[i][0] - x0, 2.f * acc[i][1] - x1,
                                2.f * acc[i][2] - x2, 2.f * acc[i][3] - x3);
        *(float4*)&D[((size_t)b * NN + r0 + ty * 4 + i) * NN + m0 + tx * 4] = o4;
    }
}

// ---------- top-20 SET selection per row (downstream is order-invariant).
__global__ __launch_bounds__(256) void k_sel(const float* __restrict__ D,
                                             int* __restrict__ idxb)
{
    int gw = blockIdx.x * 4 + (threadIdx.x >> 6);
    int lane = threadIdx.x & 63;
    const float* drow = D + (size_t)gw * NN;
    float vr[16];
#pragma unroll
    for (int j = 0; j < 16; ++j) vr[j] = drow[j * 64 + lane];

    unsigned lo = 0x007FFFFFu;  // key(-inf): cnt_gt >= 20
    unsigned hi = 0xFF800000u;  // key(+inf): cnt_gt == 0 < 20
#pragma unroll 1
    while (hi - lo > 1u) {
        unsigned mid = lo + ((hi - lo) >> 1);
        float tm = key2f(mid);
        int c = 0;
#pragma unroll
        for (int j = 0; j < 16; ++j) c += __popcll(__ballot(vr[j] > tm));
        if (c < KNN) hi = mid; else lo = mid;
    }
    float t = key2f(hi);  // V20 = 20th largest value

    int* outp = idxb + (size_t)gw * KNN;
    unsigned long long mylow = (1ull << lane) - 1ull;
    int base = 0;
#pragma unroll
    for (int j = 0; j < 16; ++j) {
        unsigned long long bmask = __ballot(vr[j] > t);
        if (vr[j] > t) outp[base + __popcll(bmask & mylow)] = j * 64 + lane;
        base += __popcll(bmask);
    }
#pragma unroll 1
    for (int j = 0; j < 16 && base < KNN; ++j) {
        unsigned long long bmask = __ballot(vr[j] == t);
        int pre = __popcll(bmask & mylow);
        if (vr[j] == t && base + pre < KNN) outp[base + pre] = j * 64 + lane;
        base += __popcll(bmask);
    }
}

// ---------- generic tiled GEMM: Y[r,o] = sum_k act(X[r*XS+k]) * W[k*OC+o] (+bias[(r>>10)*OC+o])
// X-staging via guarded float4 loads (XS%4==0; per-element k<K mask).
template<bool ACT, bool BIAS>
__global__ __launch_bounds__(256) void k_gemm(const float* __restrict__ X,
    const float* __restrict__ W, float* __restrict__ Y, int K, int OC, int XS,
    const float* __restrict__ scale, const float* __restrict__ shift,
    const float* __restrict__ bias)
{
    __shared__ float Xs[16][68];
    __shared__ float Ws[16][64];
    int r0 = blockIdx.x * 64, o0 = blockIdx.y * 64;
    int t = threadIdx.x;
    int tx = t & 15, ty = t >> 4;
    float acc[4][4] = {};
    for (int k0 = 0; k0 < K; k0 += 16) {
        __syncthreads();
        {
            int row = t >> 2, kb = (t & 3) * 4;
            float4 xv = make_float4(0.f, 0.f, 0.f, 0.f);
            if (k0 + kb < XS) xv = *(const float4*)&X[(size_t)(r0 + row) * XS + k0 + kb];
            float vv[4] = {xv.x, xv.y, xv.z, xv.w};
#pragma unroll
            for (int u = 0; u < 4; ++u) {
                int k = k0 + kb + u;
                float v = 0.f;
                if (k < K) {
                    v = vv[u];
                    if (ACT) { float z = fmaf(v, scale[k], shift[k]); v = fmaxf(z, 0.2f * z); }
                }
                Xs[kb + u][row] = v;
            }
            int kw = t >> 4, ow = (t & 15) * 4;
            float4 wv = make_float4(0.f, 0.f, 0.f, 0.f);
            if (k0 + kw < K) wv = *(const float4*)&W[(size_t)(k0 + kw) * OC + o0 + ow];
            *(float4*)&Ws[kw][ow] = wv;
        }
        __syncthreads();
#pragma unroll
        for (int k = 0; k < 16; ++k) {
            float4 a = *(const float4*)&Xs[k][ty * 4];
            float4 bb = *(const float4*)&Ws[k][tx * 4];
            float av[4] = {a.x, a.y, a.z, a.w};
            float bvv[4] = {bb.x, bb.y, bb.z, bb.w};
#pragma unroll
            for (int i = 0; i < 4; ++i)
#pragma unroll
                for (int j = 0; j < 4; ++j)
                    acc[i][j] = fmaf(av[i], bvv[j], acc[i][j]);
        }
    }
#pragma unroll
    for (int i = 0; i < 4; ++i) {
        int r = r0 + ty * 4 + i;
        float4 o4;
        float* po = (float*)&o4;
#pragma unroll
        for (int j = 0; j < 4; ++j) {
            float v = acc[i][j];
            if (BIAS) v += bias[(size_t)(r >> 10) * OC + o0 + tx * 4 + j];
            po[j] = v;
        }
        *(float4*)&Y[(size_t)r * OC + o0 + tx * 4] = o4;
    }
}

// ---------- gather neighbors, max over k, per-block BN partials (deterministic).
template<int O>
__global__ __launch_bounds__(256) void k_gather(const float* __restrict__ Z,
    const int* __restrict__ idxb, float* __restrict__ xo,
    float* __restrict__ part_s, float* __restrict__ part_q)
{
    constexpr int OL = O / 64;
    __shared__ float rs[4][O], rq[4][O];
    int b = blockIdx.y, nt = blockIdx.x;
    int t = threadIdx.x, lane = t & 63, w = t >> 6;
    float ps[OL] = {}, pq[OL] = {};
    for (int i = 0; i < 4; ++i) {
        int n = nt * 16 + w * 4 + i;
        size_t r = (size_t)b * NN + n;
        float zd[OL], ym[OL];
#pragma unroll
        for (int j = 0; j < OL; ++j) {
            int o = lane + j * 64;
            zd[j] = Z[r * (2 * O) + O + o] - Z[r * (2 * O) + o];
            ym[j] = -3.4e38f;
        }
        int midx[KNN];
        {
            const int4* ip = (const int4*)&idxb[r * KNN];
#pragma unroll
            for (int q = 0; q < 5; ++q) {
                int4 t4 = ip[q];
                midx[4 * q + 0] = t4.x; midx[4 * q + 1] = t4.y;
                midx[4 * q + 2] = t4.z; midx[4 * q + 3] = t4.w;
            }
        }
#pragma unroll
        for (int k = 0; k < KNN; ++k) {
            size_t rm = (size_t)b * NN + midx[k];
#pragma unroll
            for (int j = 0; j < OL; ++j) {
                float y = Z[rm * (2 * O) + lane + j * 64] + zd[j];
                ym[j] = fmaxf(ym[j], y);
                ps[j] += y; pq[j] = fmaf(y, y, pq[j]);
            }
        }
#pragma unroll
        for (int j = 0; j < OL; ++j) xo[r * O + lane + j * 64] = ym[j];
    }
#pragma unroll
    for (int j = 0; j < OL; ++j) { rs[w][lane + j * 64] = ps[j]; rq[w][lane + j * 64] = pq[j]; }
    __syncthreads();
    if (w == 0) {
        int blk = blockIdx.y * 64 + blockIdx.x;  // 0..2047, fixed slot per block
#pragma unroll
        for (int j = 0; j < OL; ++j) {
            int o = lane + j * 64;
            part_s[(size_t)o * 2048 + blk] = rs[0][o] + rs[1][o] + rs[2][o] + rs[3][o];
            part_q[(size_t)o * 2048 + blk] = rq[0][o] + rq[1][o] + rq[2][o] + rq[3][o];
        }
    }
}

// ---------- deterministic BN finalize from fixed-slot partials (2048 slots)
__global__ void k_bnfin2(const float* __restrict__ part_s, const float* __restrict__ part_q,
                         const float* __restrict__ g, const float* __restrict__ bb,
                         float* __restrict__ scale, float* __restrict__ shift,
                         int OC, float invM, float eps)
{
    int o = blockIdx.x * blockDim.x + threadIdx.x;
    if (o >= OC) return;
    const float* ps = part_s + (size_t)o * 2048;
    const float* pq = part_q + (size_t)o * 2048;
    float s0 = 0.f, s1 = 0.f, s2 = 0.f, s3 = 0.f;
    float q0 = 0.f, q1 = 0.f, q2 = 0.f, q3 = 0.f;
    for (int i = 0; i < 2048; i += 4) {
        s0 += ps[i]; s1 += ps[i + 1]; s2 += ps[i + 2]; s3 += ps[i + 3];
        q0 += pq[i]; q1 += pq[i + 1]; q2 += pq[i + 2]; q3 += pq[i + 3];
    }
    float s = (s0 + s1) + (s2 + s3);
    float q = (q0 + q1) + (q2 + q3);
    float mu = s * invM;
    float var = q * invM - mu * mu;
    float sc = g[o] * rsqrtf(var + eps);
    scale[o] = sc; shift[o] = bb[o] - mu * sc;
}

// ---------- conv-chain BN finalize from fixed-slot partials (128 slots, deterministic)
__global__ void k_bnfin3(const float* __restrict__ part_s, const float* __restrict__ part_q,
                         const float* __restrict__ g, const float* __restrict__ bb,
                         float* __restrict__ scale, float* __restrict__ shift,
                         int OC, float invM, float eps)
{
    int o = blockIdx.x * blockDim.x + threadIdx.x;
    if (o >= OC) return;
    const float* ps = part_s + (size_t)o * 128;
    const float* pq = part_q + (size_t)o * 128;
    float s0 = 0.f, s1 = 0.f, s2 = 0.f, s3 = 0.f;
    float q0 = 0.f, q1 = 0.f, q2 = 0.f, q3 = 0.f;
    for (int i = 0; i < 128; i += 4) {
        s0 += ps[i]; s1 += ps[i + 1]; s2 += ps[i + 2]; s3 += ps[i + 3];
        q0 += pq[i]; q1 += pq[i + 1]; q2 += pq[i + 2]; q3 += pq[i + 3];
    }
    float s = (s0 + s1) + (s2 + s3);
    float q = (q0 + q1) + (q2 + q3);
    float mu = s * invM;
    float var = q * invM - mu * mu;
    float sc = g[o] * rsqrtf(var + eps);
    scale[o] = sc; shift[o] = bb[o] - mu * sc;
}

// ---------- elementwise BN apply + lrelu (in place)
__global__ void k_bnapply(float* __restrict__ x, const float* __restrict__ scale,
                          const float* __restrict__ shift, int total, int O)
{
    int i = blockIdx.x * 256 + threadIdx.x;
    if (i >= total) return;
    int o = i & (O - 1);
    x[i] = lrelu(fmaf(x[i], scale[o], shift[o]));
}

// ---------- BN apply + lrelu + row-norm for O=64 tensors (xt1/xt2), float4.
__global__ __launch_bounds__(256) void k_bnapply_rn(float* __restrict__ x,
    const float* __restrict__ scale, const float* __restrict__ shift,
    float* __restrict__ xx)
{
    __shared__ float red[16][17];
    int t = threadIdx.x;
    int i4 = blockIdx.x * 256 + t;       // quad index; row = i4>>4 (block-aligned)
    int q = t & 15, lrow = t >> 4;
    float4 v = ((float4*)x)[i4];
    int o = q * 4;
    v.x = lrelu(fmaf(v.x, scale[o + 0], shift[o + 0]));
    v.y = lrelu(fmaf(v.y, scale[o + 1], shift[o + 1]));
    v.z = lrelu(fmaf(v.z, scale[o + 2], shift[o + 2]));
    v.w = lrelu(fmaf(v.w, scale[o + 3], shift[o + 3]));
    ((float4*)x)[i4] = v;
    float part = fmaf(v.w, v.w, fmaf(v.z, v.z, fmaf(v.y, v.y, v.x * v.x)));
    red[lrow][q] = part;
    __syncthreads();
    if (t < 16) {
        float s = 0.f;
#pragma unroll
        for (int j = 0; j < 16; ++j) s += red[t][j];
        xx[blockIdx.x * 16 + t] = s;
    }
}

// ---------- concat x1|x2|x3 -> fcat (B*N, 256)
__global__ void k_concat(const float* __restrict__ x1, const float* __restrict__ x2,
                         const float* __restrict__ x3, float* __restrict__ f)
{
    int i = blockIdx.x * 256 + threadIdx.x;
    if (i >= RTOT * 256) return;
    int r = i >> 8, c = i & 255;
    float v;
    if (c < 64) v = x1[(size_t)r * 64 + c];
    else if (c < 128) v = x2[(size_t)r * 64 + c - 64];
    else v = x3[(size_t)r * 128 + c - 128];
    f[(size_t)i] = v;
}

// ---------- LayerNorm stats per b over (N,40) of h (stride 64)
__global__ __launch_bounds__(256) void k_lnstats(const float* __restrict__ h, float* __restrict__ st)
{
    __shared__ float rsm[256], rqm[256];
    int b = blockIdx.x, t = threadIdx.x;
    float s = 0.f, q = 0.f;
    for (int i = t; i < 40960; i += 256) {
        int n = i / 40, o = i - n * 40;
        float v = h[((size_t)b * NN + n) * 64 + o];
        s += v; q = fmaf(v, v, q);
    }
    rsm[t] = s; rqm[t] = q; __syncthreads();
    for (int off = 128; off; off >>= 1) {
        if (t < off) { rsm[t] += rsm[t + off]; rqm[t] += rqm[t + off]; }
        __syncthreads();
    }
    if (t == 0) {
        float mu = rsm[0] / 40960.f;
        float var = rqm[0] / 40960.f - mu * mu;
        st[2 * b] = mu; st[2 * b + 1] = rsqrtf(var + 1e-6f);
    }
}

// ---------- LayerNorm apply + relu (in place on h -> encoder)
__global__ void k_lnapply(float* __restrict__ h, const float* __restrict__ lnw,
                          const float* __restrict__ lnb, const float* __restrict__ st)
{
    int i = blockIdx.x * 256 + threadIdx.x;
    if (i >= NB * NN * 40) return;
    int b = i / 40960, rem = i - b * 40960, n = rem / 40, o = rem - n * 40;
    float mu = st[2 * b], rstd = st[2 * b + 1];
    size_t a = ((size_t)b * NN + n) * 64 + o;
    float v = fmaf((h[a] - mu) * rstd, lnw[n * 40 + o], lnb[n * 40 + o]);
    h[a] = fmaxf(v, 0.f);
}

// ---------- u_hat fused with s1 = sum_p u. ONE wave per block, grid (64 pc, 40 l).
__global__ __launch_bounds__(64) void k_uhat(const float* __restrict__ enc,
    const float* __restrict__ caps, float* __restrict__ U, float* __restrict__ pbu)
{
    __shared__ float clt[40 * 68];
    int pc = blockIdx.x, l = blockIdx.y;
    int lane = threadIdx.x;
    int vg = lane & 7, bg = lane >> 3;
    int v0 = vg * 8, b0 = bg * 4;
    float spart[4][8] = {};
#pragma unroll 1
    for (int pi = 0; pi < 16; ++pi) {
        int p = pc * 16 + pi;
        const float4* cp4 = (const float4*)(caps + ((size_t)l * NN + p) * 2560);
#pragma unroll
        for (int k = 0; k < 10; ++k) {
            int i4 = lane + k * 64;        // 0..639
            float4 cv = cp4[i4];
            int e0 = i4 * 4;
            int v = e0 / 40;
            int d0 = e0 - v * 40;
            clt[(d0 + 0) * 68 + v] = cv.x;
            clt[(d0 + 1) * 68 + v] = cv.y;
            clt[(d0 + 2) * 68 + v] = cv.z;
            clt[(d0 + 3) * 68 + v] = cv.w;
        }
        float acc[4][8] = {};
#pragma unroll
        for (int d4 = 0; d4 < 10; ++d4) {
            float4 e4[4];
#pragma unroll
            for (int i = 0; i < 4; ++i)
                e4[i] = *(const float4*)&enc[((size_t)(b0 + i) * NN + p) * 64 + d4 * 4];
#pragma unroll
            for (int dd = 0; dd < 4; ++dd) {
                int d = d4 * 4 + dd;
                float4 c0 = *(const float4*)&clt[d * 68 + v0];
                float4 c1 = *(const float4*)&clt[d * 68 + v0 + 4];
                float cv[8] = {c0.x, c0.y, c0.z, c0.w, c1.x, c1.y, c1.z, c1.w};
#pragma unroll
                for (int i = 0; i < 4; ++i) {
                    float e = ((const float*)&e4[i])[dd];
#pragma unroll
                    for (int j = 0; j < 8; ++j)
                        acc[i][j] = fmaf(e, cv[j], acc[i][j]);
                }
            }
        }
#pragma unroll
        for (int i = 0; i < 4; ++i) {
            float* up = &U[((size_t)(b0 + i) * NN + p) * 2560 + l * 64 + v0];
            float4 o0 = make_float4(acc[i][0], acc[i][1], acc[i][2], acc[i][3]);
            float4 o1 = make_float4(acc[i][4], acc[i][5], acc[i][6], acc[i][7]);
            *(float4*)up = o0;
            *(float4*)(up + 4) = o1;
#pragma unroll
            for (int j = 0; j < 8; ++j) spart[i][j] += acc[i][j];
        }
    }
    float* pb = pbu + (size_t)pc * 81920;
#pragma unroll
    for (int i = 0; i < 4; ++i) {
        float4 s0 = make_float4(spart[i][0], spart[i][1], spart[i][2], spart[i][3]);
        float4 s1 = make_float4(spart[i][4], spart[i][5], spart[i][6], spart[i][7]);
        float* dst = &pb[(size_t)(b0 + i) * 2560 + l * 64 + v0];
        *(float4*)dst = s0;
        *(float4*)(dst + 4) = s1;
    }
}

// ---------- routing pass, float4-vectorized U stream. eo[] eliminated (exp recomputed)
// to cut VGPR below 102 -> 5 waves/SIMD. Deterministic (identical arithmetic).
template<int MODE>
__global__ __launch_bounds__(256, 5) void k_route(const float* __restrict__ U,
    const float* __restrict__ vprev, const float* __restrict__ bin,
    float* __restrict__ bout, float* __restrict__ pbuf)
{
    __shared__ float vl[2560];
    __shared__ float red[4][1280];
    int b = blockIdx.x, pc = blockIdx.y;
    int t = threadIdx.x, lane = t & 63, w = t >> 6;
    for (int i = t; i < 2560; i += 256) vl[i] = vprev[(size_t)b * 2560 + i];
    __syncthreads();
    float4 acc[10];
#pragma unroll
    for (int it = 0; it < 10; ++it) acc[it] = make_float4(0.f, 0.f, 0.f, 0.f);
    int lgrp = lane >> 4;
#pragma unroll 1
    for (int pi = 0; pi < 8; ++pi) {
        int p = pc * 32 + w * 8 + pi;
        const float4* up4 = (const float4*)(U + ((size_t)b * NN + p) * 2560);
        float4 u[10];
#pragma unroll
        for (int it = 0; it < 10; ++it) u[it] = up4[it * 64 + lane];
        float pd[10];
#pragma unroll
        for (int it = 0; it < 10; ++it) {
            float4 vv = *(const float4*)&vl[it * 256 + lane * 4];
            float s = u[it].x * vv.x;
            s = fmaf(u[it].y, vv.y, s);
            s = fmaf(u[it].z, vv.z, s);
            s = fmaf(u[it].w, vv.w, s);
            s += __shfl_xor(s, 1, 64);
            s += __shfl_xor(s, 2, 64);
            s += __shfl_xor(s, 4, 64);
            s += __shfl_xor(s, 8, 64);
            pd[it] = s;
        }
        if (MODE == 1) {
            if ((lane & 15) == 0) {
#pragma unroll
                for (int it = 0; it < 10; ++it)
                    bout[((size_t)b * 40 + it * 4 + lgrp) * NN + p] = pd[it];
            }
        } else {
#pragma unroll
            for (int it = 0; it < 10; ++it)
                pd[it] += bin[((size_t)b * 40 + it * 4 + lgrp) * NN + p];
        }
        float mx = -3.4e38f;
#pragma unroll
        for (int it = 0; it < 10; ++it) {
            float m = pd[it];
            m = fmaxf(m, __shfl_xor(m, 16, 64));
            m = fmaxf(m, __shfl_xor(m, 32, 64));
            mx = fmaxf(mx, m);
        }
        float se = 0.f;
#pragma unroll
        for (int it = 0; it < 10; ++it) {
            float e = expf(pd[it] - mx);
            float sg = e;
            sg += __shfl_xor(sg, 16, 64);
            sg += __shfl_xor(sg, 32, 64);
            se += sg;
        }
        float inv = 1.f / se;
#pragma unroll
        for (int it = 0; it < 10; ++it) {
            float wgt = expf(pd[it] - mx) * inv;
            acc[it].x = fmaf(wgt, u[it].x, acc[it].x);
            acc[it].y = fmaf(wgt, u[it].y, acc[it].y);
            acc[it].z = fmaf(wgt, u[it].z, acc[it].z);
            acc[it].w = fmaf(wgt, u[it].w, acc[it].w);
        }
    }
    float* pb = pbuf + ((size_t)pc * NB + b) * 2560;
#pragma unroll 1
    for (int h = 0; h < 2; ++h) {
        __syncthreads();
#pragma unroll
        for (int it = 0; it < 5; ++it)
            *(float4*)&red[w][it * 256 + lane * 4] = acc[h * 5 + it];
        __syncthreads();
        if (w == 0) {
#pragma unroll
            for (int it = 0; it < 5; ++it) {
                int idx = it * 256 + lane * 4;
                float4 a0 = *(const float4*)&red[0][idx];
                float4 a1 = *(const float4*)&red[1][idx];
                float4 a2 = *(const float4*)&red[2][idx];
                float4 a3 = *(const float4*)&red[3][idx];
                float4 o = make_float4((a0.x + a1.x) + (a2.x + a3.x),
                                       (a0.y + a1.y) + (a2.y + a3.y),
                                       (a0.z + a1.z) + (a2.z + a3.z),
                                       (a0.w + a1.w) + (a2.w + a3.w));
                *(float4*)&pb[h * 1280 + idx] = o;
            }
        }
    }
}

// ---------- fused: reduce partials over NCH chunks + squash -> vb. Deterministic.
template<int NCH>
__global__ __launch_bounds__(256) void k_sredsq(const float* __restrict__ pbuf,
    float* __restrict__ vout, float premul)
{
    __shared__ float red[16][17];
    __shared__ float fac[16];
    int t = threadIdx.x;
    int i4 = blockIdx.x * 256 + t;       // quad index over NB*40*16 = 20480
    int q = t & 15, lrow = t >> 4;
    const float4* pb4 = (const float4*)pbuf;
    float4 s = make_float4(0.f, 0.f, 0.f, 0.f);
#pragma unroll 4
    for (int pc = 0; pc < NCH; ++pc) {
        float4 v = pb4[(size_t)pc * (NB * 640) + i4];
        s.x += v.x; s.y += v.y; s.z += v.z; s.w += v.w;
    }
    s.x *= premul; s.y *= premul; s.z *= premul; s.w *= premul;
    float part = fmaf(s.w, s.w, fmaf(s.z, s.z, fmaf(s.y, s.y, s.x * s.x)));
    red[lrow][q] = part;
    __syncthreads();
    if (t < 16) {
        float sn = 0.f;
#pragma unroll
        for (int j = 0; j < 16; ++j) sn += red[t][j];
        fac[t] = sn / ((1.f + sn) * sqrtf(sn));
    }
    __syncthreads();
    float f = fac[lrow];
    ((float4*)vout)[i4] = make_float4(s.x * f, s.y * f, s.z * f, s.w * f);
}

// ---------- emb = enc @ latent, max over v
__global__ __launch_bounds__(256) void k_emb(const float* __restrict__ enc,
    const float* __restrict__ lat, float* __restrict__ embm)
{
    __shared__ float latl[2560];
    int b = blockIdx.x, pt = blockIdx.y;
    int t = threadIdx.x, lane = t & 63, w = t >> 6;
    for (int i = t; i < 2560; i += 256) latl[i] = lat[(size_t)b * 2560 + i];
    __syncthreads();
    for (int i = 0; i < 32; ++i) {
        int p = pt * 128 + w * 32 + i;
        const float* ep = enc + ((size_t)b * NN + p) * 64;
        float acc = 0.f;
#pragma unroll
        for (int d = 0; d < 40; ++d) acc = fmaf(ep[d], latl[d * 64 + lane], acc);
        float mx = acc;
#pragma unroll
        for (int s = 32; s; s >>= 1) mx = fmaxf(mx, __shfl_xor(mx, s, 64));
        if (lane == 0) embm[(size_t)b * NN + p] = mx;
    }
}

// ---------- base2 with integrated lab
__global__ __launch_bounds__(256) void k_base2(const float* __restrict__ em,
    const float* __restrict__ lin, const float* __restrict__ cw1,
    const float* __restrict__ cg1, const float* __restrict__ cb1,
    const float* __restrict__ cw2, float* __restrict__ base)
{
    __shared__ float eml[1024];
    __shared__ float lbl[64];
    int b = blockIdx.x, t = threadIdx.x;
    for (int i = t; i < 1024; i += 256) eml[i] = em[(size_t)b * NN + i];
    if (t < 64) {
        int o = t;
        float ys[32]; float s = 0.f, q = 0.f;
#pragma unroll
        for (int bb = 0; bb < 32; ++bb) {
            float y = 0.f;
#pragma unroll
            for (int c = 0; c < 16; ++c) y = fmaf(lin[bb * 16 + c], cw1[o * 16 + c], y);
            ys[bb] = y; s += y; q = fmaf(y, y, q);
        }
        float mu = s / 32.f, var = q / 32.f - mu * mu;
        float sc = cg1[o] * rsqrtf(var + 1e-5f);
        float sh = cb1[o] - mu * sc;
        lbl[o] = lrelu(fmaf(ys[b], sc, sh));
    }
    __syncthreads();
    const float* wr = cw2 + (size_t)t * 1128;
    float acc = 0.f;
    for (int c = 0; c < 1024; ++c) acc = fmaf(wr[c], eml[c], acc);
#pragma unroll
    for (int c = 0; c < 64; ++c) acc = fmaf(wr[1024 + c], lbl[c], acc);
    base[b * 256 + t] = acc;
}

// ---------- column stats over rows, fixed-slot partials (deterministic)
__global__ __launch_bounds__(256) void k_colstats2(const float* __restrict__ Y,
    float* __restrict__ part_s, float* __restrict__ part_q, int OC)
{
    __shared__ float rs[4][64], rq[4][64];
    int chunk = blockIdx.x, o0 = blockIdx.y * 64;
    int t = threadIdx.x, lane = t & 63, w = t >> 6;
    int o = o0 + lane;
    float s = 0.f, q = 0.f;
    for (int j = 0; j < 64; ++j) {
        int r = chunk * 256 + w * 64 + j;
        float v = Y[(size_t)r * OC + o];
        s += v; q = fmaf(v, v, q);
    }
    rs[w][lane] = s; rq[w][lane] = q;
    __syncthreads();
    if (w == 0) {
        part_s[(size_t)o * 128 + chunk] = rs[0][lane] + rs[1][lane] + rs[2][lane] + rs[3][lane];
        part_q[(size_t)o * 128 + chunk] = rq[0][lane] + rq[1][lane] + rq[2][lane] + rq[3][lane];
    }
}

// ---------- final: BN+lrelu+transpose to out (B,50,N)
__global__ void k_out(const float* __restrict__ Y, const float* __restrict__ scale,
                      const float* __restrict__ shift, float* __restrict__ out)
{
    int i = blockIdx.x * 256 + threadIdx.x;
    if (i >= NB * 50 * NN) return;
    int n = i & 1023, rest = i >> 10;
    int o = rest % 50, b = rest / 50;
    float y = Y[((size_t)b * NN + n) * 64 + o];
    out[i] = lrelu(fmaf(y, scale[o], shift[o]));
}

extern "C" void kernel_launch(void* const* d_in, const int* in_sizes, int n_in,
                              void* d_out, int out_size, void* d_ws, size_t ws_size,
                              hipStream_t stream)
{
    const float* data = (const float*)d_in[0];
    const float* lin  = (const float*)d_in[1];
    const float* dw1  = (const float*)d_in[2];
    const float* dg1  = (const float*)d_in[3];
    const float* db1  = (const float*)d_in[4];
    const float* dw2  = (const float*)d_in[5];
    const float* dg2  = (const float*)d_in[6];
    const float* db2  = (const float*)d_in[7];
    const float* dw3  = (const float*)d_in[8];
    const float* dg3  = (const float*)d_in[9];
    const float* db3  = (const float*)d_in[10];
    const float* lw   = (const float*)d_in[11];
    const float* lnw  = (const float*)d_in[12];
    const float* lnb  = (const float*)d_in[13];
    const float* caps = (const float*)d_in[14];
    const float* cw1  = (const float*)d_in[15];
    const float* cg1  = (const float*)d_in[16];
    const float* cb1  = (const float*)d_in[17];
    const float* cw2  = (const float*)d_in[18];
    const float* cg2  = (const float*)d_in[19];
    const float* cb2  = (const float*)d_in[20];
    const float* cw3  = (const float*)d_in[21];
    const float* cw4  = (const float*)d_in[22];
    const float* cg4  = (const float*)d_in[23];
    const float* cb4  = (const float*)d_in[24];
    const float* cw5  = (const float*)d_in[25];
    const float* cg5  = (const float*)d_in[26];
    const float* cb5  = (const float*)d_in[27];
    float* out = (float*)d_out;
    float* ws = (float*)d_ws;

    float* big  = ws + O_BIG;
    float* xt0  = ws + O_XT0;
    float* xt1  = ws + O_XT1;
    float* xt2  = ws + O_XT2;
    float* xt3  = ws + O_XT3;
    float* xxp  = ws + O_XX;
    int*   idxb = (int*)(ws + O_IDX);
    float* wc1  = ws + O_WC1;
    float* wc2  = ws + O_WC2;
    float* wc3  = ws + O_WC3;
    float* lwt  = ws + O_LWT;
    float* c2t  = ws + O_C2T;
    float* c3t  = ws + O_C3T;
    float* c4t  = ws + O_C4T;
    float* c5t  = ws + O_C5T;
    float* hbuf = ws + O_H;
    float* lnst = ws + O_LNST;
    float* scl  = ws + O_SCL;
    float* shf  = ws + O_SHF;
    float* vb   = ws + O_VB;
    float* bij  = ws + O_BIJ;
    float* embm = ws + O_EMB;
    float* basep= ws + O_BASE;
    float* psP  = ws + O_PS;        // partials (alias bij; disjoint lifetimes)
    float* pqP  = ws + O_PQ;
    float* pbuf = ws + O_PB;        // routing partials (alias xt1/xt2; dead after concat)
    float* pbu  = ws + O_PBU;       // uhat s1 partials (same region, used before routing pbuf)
    float* Dbuf = big;              // distances, then Z, then fcat/u_hat/ybufs
    float* Z    = big;
    float* U    = big;
    float* yb1  = big;
    float* yb2  = big + 8388608;

    // ---- weight prep (single kernel) + data transpose w/ fused norm
    k_wtall<<<618, 256, 0, stream>>>(dw1, dw2, dw3, lw, cw2, cw3, cw4, cw5,
                                     wc1, wc2, wc3, lwt, c2t, c3t, c4t, c5t);
    k_data_t<<<128, 256, 0, stream>>>(data, xt0, xxp);

    // ---- stage 1 (C=3 -> O=64)
    k_dist<4><<<dim3(16, 16, 32), 256, 0, stream>>>(xt0, xxp, Dbuf);
    k_sel<<<8192, 256, 0, stream>>>(Dbuf, idxb);
    k_gemm<false, false><<<dim3(512, 2), 256, 0, stream>>>(xt0, wc1, Z, 3, 128, 4, nullptr, nullptr, nullptr);
    k_gather<64><<<dim3(64, 32), 256, 0, stream>>>(Z, idxb, xt1, psP, pqP);
    k_bnfin2<<<1, 64, 0, stream>>>(psP, pqP, dg1, db1, scl, shf, 64, 1.f / 655360.f, 1e-5f);
    k_bnapply_rn<<<2048, 256, 0, stream>>>(xt1, scl, shf, xxp);

    // ---- stage 2 (C=64 -> O=64)
    k_dist<64><<<dim3(16, 16, 32), 256, 0, stream>>>(xt1, xxp, Dbuf);
    k_sel<<<8192, 256, 0, stream>>>(Dbuf, idxb);
    k_gemm<false, false><<<dim3(512, 2), 256, 0, stream>>>(xt1, wc2, Z, 64, 128, 64, nullptr, nullptr, nullptr);
    k_gather<64><<<dim3(64, 32), 256, 0, stream>>>(Z, idxb, xt2, psP, pqP);
    k_bnfin2<<<1, 64, 0, stream>>>(psP, pqP, dg2, db2, scl, shf, 64, 1.f / 655360.f, 1e-5f);
    k_bnapply_rn<<<2048, 256, 0, stream>>>(xt2, scl, shf, xxp);

    // ---- stage 3 (C=64 -> O=128)
    k_dist<64><<<dim3(16, 16, 32), 256, 0, stream>>>(xt2, xxp, Dbuf);
    k_sel<<<8192, 256, 0, stream>>>(Dbuf, idxb);
    k_gemm<false, false><<<dim3(512, 4), 256, 0, stream>>>(xt2, wc3, Z, 64, 256, 64, nullptr, nullptr, nullptr);
    k_gather<128><<<dim3(64, 32), 256, 0, stream>>>(Z, idxb, xt3, psP, pqP);
    k_bnfin2<<<1, 128, 0, stream>>>(psP, pqP, dg3, db3, scl, shf, 128, 1.f / 655360.f, 1e-5f);
    k_bnapply<<<16384, 256, 0, stream>>>(xt3, scl, shf, RTOT * 128, 128);

    // ---- feat concat, linear, LayerNorm (-> encoder in hbuf)
    k_concat<<<32768, 256, 0, stream>>>(xt1, xt2, xt3, big);
    k_gemm<false, false><<<dim3(512, 1), 256, 0, stream>>>(big, lwt, hbuf, 256, 64, 256, nullptr, nullptr, nullptr);
    k_lnstats<<<32, 256, 0, stream>>>(hbuf, lnst);
    k_lnapply<<<5120, 256, 0, stream>>>(hbuf, lnw, lnb, lnst);

    // ---- capsules (xt1..xt3 now dead -> pbu/pbuf alias them)
    k_uhat<<<dim3(64, 40), 64, 0, stream>>>(hbuf, caps, U, pbu);
    k_sredsq<64><<<80, 256, 0, stream>>>(pbu, vb, 1.f / 40.f);
    k_route<1><<<dim3(32, 32), 256, 0, stream>>>(U, vb, nullptr, bij, pbuf);
    k_sredsq<32><<<80, 256, 0, stream>>>(pbuf, vb, 1.f);
    k_route<2><<<dim3(32, 32), 256, 0, stream>>>(U, vb, bij, nullptr, pbuf);
    k_sredsq<32><<<80, 256, 0, stream>>>(pbuf, vb, 1.f);

    // ---- emb, base2 (lab integrated)
    k_emb<<<dim3(32, 8), 256, 0, stream>>>(hbuf, vb, embm);
    k_base2<<<32, 256, 0, stream>>>(embm, lin, cw1, cg1, cb1, cw2, basep);

    // ---- conv chain (deterministic fixed-slot BN partials)
    k_gemm<false, true><<<dim3(512, 4), 256, 0, stream>>>(hbuf, c2t, yb1, 40, 256, 64, nullptr, nullptr, basep);
    k_colstats2<<<dim3(128, 4), 256, 0, stream>>>(yb1, psP, pqP, 256);
    k_bnfin3<<<1, 256, 0, stream>>>(psP, pqP, cg2, cb2, scl, shf, 256, 1.f / 32768.f, 1e-5f);

    k_gemm<true, false><<<dim3(512, 4), 256, 0, stream>>>(yb1, c3t, yb2, 256, 256, 256, scl, shf, nullptr);
    k_colstats2<<<dim3(128, 4), 256, 0, stream>>>(yb2, psP, pqP, 256);
    k_bnfin3<<<1, 256, 0, stream>>>(psP, pqP, cg2, cb2, scl, shf, 256, 1.f / 32768.f, 1e-5f);

    k_gemm<true, false><<<dim3(512, 2), 256, 0, stream>>>(yb2, c4t, yb1, 256, 128, 256, scl, shf, nullptr);
    k_colstats2<<<dim3(128, 2), 256, 0, stream>>>(yb1, psP, pqP, 128);
    k_bnfin3<<<1, 256, 0, stream>>>(psP, pqP, cg4, cb4, scl, shf, 128, 1.f / 32768.f, 1e-5f);

    k_gemm<true, false><<<dim3(512, 1), 256, 0, stream>>>(yb1, c5t, yb2, 128, 64, 128, scl, shf, nullptr);
    k_colstats2<<<dim3(128, 1), 256, 0, stream>>>(yb2, psP, pqP, 64);
    k_bnfin3<<<1, 256, 0, stream>>>(psP, pqP, cg5, cb5, scl, shf, 50, 1.f / 32768.f, 1e-5f);

    k_out<<<6400, 256, 0, stream>>>(yb2, scl, shf, out);
}

// Round 16
// 1628.725 us; speedup vs baseline: 1.1242x; 1.1242x over previous
//
#include <hip/hip_runtime.h>
#include <math.h>

constexpr int NB = 32, NN = 1024, KNN = 20;
constexpr int RTOT = NB * NN; // 32768

// ---------------- workspace offsets (in floats) ----------------
constexpr size_t SZ_BIG = (size_t)NB * NN * 40 * 64;      // 83,886,080 (u_hat / D / Z / fcat / ybufs)
constexpr size_t O_BIG  = 0;
constexpr size_t O_XT0  = O_BIG + SZ_BIG;                  // (B,N,4) data transposed
constexpr size_t O_XT1  = O_XT0 + (size_t)RTOT * 4;        // (B,N,64)
constexpr size_t O_XT2  = O_XT1 + (size_t)RTOT * 64;       // (B,N,64)
constexpr size_t O_XT3  = O_XT2 + (size_t)RTOT * 64;       // (B,N,128)
constexpr size_t O_XX   = O_XT3 + (size_t)RTOT * 128;      // row norms
constexpr size_t O_IDX  = O_XX + RTOT;                     // int (B,N,20)
constexpr size_t O_WC1  = O_IDX + (size_t)RTOT * KNN;      // 4x128
constexpr size_t O_WC2  = O_WC1 + 512;                     // 64x128
constexpr size_t O_WC3  = O_WC2 + 8192;                    // 64x256
constexpr size_t O_LWT  = O_WC3 + 16384;                   // 256x64
constexpr size_t O_C2T  = O_LWT + 16384;                   // 40x256
constexpr size_t O_C3T  = O_C2T + 10240;                   // 256x256
constexpr size_t O_C4T  = O_C3T + 65536;                   // 256x128
constexpr size_t O_C5T  = O_C4T + 32768;                   // 128x64
constexpr size_t O_H    = O_C5T + 8192;                    // (B,N,64) h / encoder
constexpr size_t O_LNST = O_H + (size_t)RTOT * 64;         // 2 per b
constexpr size_t O_BSUM = O_LNST + 64;
constexpr size_t O_BSQ  = O_BSUM + 256;
constexpr size_t O_SCL  = O_BSQ + 256;
constexpr size_t O_SHF  = O_SCL + 256;
constexpr size_t O_SACC = O_SHF + 256;                     // (B,40,64) (unused now)
constexpr size_t O_VB   = O_SACC + 81920;                  // (B,40,64)
constexpr size_t O_BIJ  = O_VB + 81920;                    // (B,40,1024) routing b; ALSO partials
constexpr size_t O_EMB  = O_BIJ + (size_t)NB * 40 * NN;    // (B,N)
constexpr size_t O_LAB  = O_EMB + RTOT;                    // (B,64) (unused now)
constexpr size_t O_BASE = O_LAB + 2048;                    // (B,256)
// BN partials alias bij (lifetimes disjoint)
constexpr size_t O_PS   = O_BIJ;                           // 128 * 2048 (stage BN) / 256*128 (conv BN)
constexpr size_t O_PQ   = O_BIJ + 262144;
// partial buffers alias xt1..xt3 (dead after k_concat):
constexpr size_t O_PB   = O_XT1;   // routing partials: 32*81920 floats
constexpr size_t O_PBU  = O_XT1;   // uhat s-sum partials: 64*81920 floats

__device__ __forceinline__ float lrelu(float z) { return fmaxf(z, 0.2f * z); }

// sortable-uint key <-> float (ascending key == ascending float)
__device__ __forceinline__ float key2f(unsigned u)
{
    unsigned b = (u & 0x80000000u) ? (u ^ 0x80000000u) : ~u;
    return __uint_as_float(b);
}

// ---------- all weight transposes in ONE kernel (blockIdx-range dispatch)
__device__ __forceinline__ void wt_do(const float* __restrict__ src, float* __restrict__ dst,
                                      int i, int K, int On, int SS, int coff, int DS, int ooff, int Oreal)
{
    if (i >= K * On) return;
    int c = i / On, o = i - c * On;
    dst[(size_t)c * DS + ooff + o] = (o < Oreal) ? src[(size_t)o * SS + coff + c] : 0.f;
}

__global__ __launch_bounds__(256) void k_wtall(
    const float* __restrict__ dw1, const float* __restrict__ dw2, const float* __restrict__ dw3,
    const float* __restrict__ lw,  const float* __restrict__ cw2, const float* __restrict__ cw3,
    const float* __restrict__ cw4, const float* __restrict__ cw5,
    float* __restrict__ wc1, float* __restrict__ wc2, float* __restrict__ wc3,
    float* __restrict__ lwt, float* __restrict__ c2t, float* __restrict__ c3t,
    float* __restrict__ c4t, float* __restrict__ c5t)
{
    int bid = blockIdx.x, t = threadIdx.x;
    if      (bid < 1)   wt_do(dw1, wc1, (bid - 0) * 256 + t,   3, 64, 6, 0, 128, 0, 64);
    else if (bid < 2)   wt_do(dw1, wc1, (bid - 1) * 256 + t,   3, 64, 6, 3, 128, 64, 64);
    else if (bid < 18)  wt_do(dw2, wc2, (bid - 2) * 256 + t,   64, 64, 128, 0, 128, 0, 64);
    else if (bid < 34)  wt_do(dw2, wc2, (bid - 18) * 256 + t,  64, 64, 128, 64, 128, 64, 64);
    else if (bid < 66)  wt_do(dw3, wc3, (bid - 34) * 256 + t,  64, 128, 128, 0, 256, 0, 128);
    else if (bid < 98)  wt_do(dw3, wc3, (bid - 66) * 256 + t,  64, 128, 128, 64, 256, 128, 128);
    else if (bid < 162) wt_do(lw,  lwt, (bid - 98) * 256 + t,  256, 64, 256, 0, 64, 0, 40);
    else if (bid < 202) wt_do(cw2, c2t, (bid - 162) * 256 + t, 40, 256, 1128, 1088, 256, 0, 256);
    else if (bid < 458) wt_do(cw3, c3t, (bid - 202) * 256 + t, 256, 256, 256, 0, 256, 0, 256);
    else if (bid < 586) wt_do(cw4, c4t, (bid - 458) * 256 + t, 256, 128, 256, 0, 128, 0, 128);
    else                wt_do(cw5, c5t, (bid - 586) * 256 + t, 128, 64, 128, 0, 64, 0, 50);
}

// ---------- data (B,3,N) -> xt0 (B,N,4), fused row-norm
__global__ void k_data_t(const float* __restrict__ d, float* __restrict__ xt,
                         float* __restrict__ xx)
{
    int i = blockIdx.x * 256 + threadIdx.x;
    if (i >= RTOT) return;
    int b = i >> 10, n = i & 1023;
    float s = 0.f;
#pragma unroll
    for (int c = 0; c < 3; ++c) {
        float v = d[((size_t)b * 3 + c) * NN + n];
        xt[(size_t)i * 4 + c] = v;
        s = fmaf(v, v, s);
    }
    xt[(size_t)i * 4 + 3] = 0.f;
    xx[i] = s;
}

// ---------- batched pairwise-score GEMM: D[b,r,m] = 2 * x_r . x_m - ||x_m||^2
// Staging via guarded float4 loads (XS%4==0, kb%4==0 -> in-row 16B).
template<int CS>
__global__ __launch_bounds__(256) void k_dist(const float* __restrict__ X,
    const float* __restrict__ xx, float* __restrict__ D)
{
    __shared__ float As[16][68];
    __shared__ float Bs[16][68];
    int b = blockIdx.z;
    int r0 = blockIdx.x * 64, m0 = blockIdx.y * 64;
    const float* Xb = X + (size_t)b * NN * CS;
    int t = threadIdx.x;
    int tx = t & 15, ty = t >> 4;
    float acc[4][4] = {};
    for (int k0 = 0; k0 < CS; k0 += 16) {
        __syncthreads();
        {
            int row = t >> 2, kb = (t & 3) * 4;
            float4 a4 = make_float4(0.f, 0.f, 0.f, 0.f);
            float4 b4 = make_float4(0.f, 0.f, 0.f, 0.f);
            if (k0 + kb < CS) {
                a4 = *(const float4*)&Xb[(size_t)(r0 + row) * CS + k0 + kb];
                b4 = *(const float4*)&Xb[(size_t)(m0 + row) * CS + k0 + kb];
            }
            As[kb + 0][row] = a4.x; As[kb + 1][row] = a4.y;
            As[kb + 2][row] = a4.z; As[kb + 3][row] = a4.w;
            Bs[kb + 0][row] = b4.x; Bs[kb + 1][row] = b4.y;
            Bs[kb + 2][row] = b4.z; Bs[kb + 3][row] = b4.w;
        }
        __syncthreads();
#pragma unroll
        for (int k = 0; k < 16; ++k) {
            float4 a = *(const float4*)&As[k][ty * 4];
            float4 bb = *(const float4*)&Bs[k][tx * 4];
            float av[4] = {a.x, a.y, a.z, a.w};
            float bv[4] = {bb.x, bb.y, bb.z, bb.w};
#pragma unroll
            for (int i = 0; i < 4; ++i)
#pragma unroll
                for (int j = 0; j < 4; ++j)
                    acc[i][j] = fmaf(av[i], bv[j], acc[i][j]);
        }
    }
    const float* xxb = xx + b * NN + m0 + tx * 4;
    float x0 = xxb[0], x1 = xxb[1], x2 = xxb[2], x3 = xxb[3];
#pragma unroll
    for (int i = 0; i < 4; ++i) {
        float4 o4 = make_float4(2.f * acc[i][0] - x0, 2.f * acc[i][1] - x1,
                                2.f * acc[i][2] - x2, 2.f * acc[i][3] - x3);
        *(float4*)&D[((size_t)b * NN + r0 + ty * 4 + i) * NN + m0 + tx * 4] = o4;
    }
}

// ---------- top-20 SET selection per row (downstream is order-invariant).
__global__ __launch_bounds__(256) void k_sel(const float* __restrict__ D,
                                             int* __restrict__ idxb)
{
    int gw = blockIdx.x * 4 + (threadIdx.x >> 6);
    int lane = threadIdx.x & 63;
    const float* drow = D + (size_t)gw * NN;
    float vr[16];
#pragma unroll
    for (int j = 0; j < 16; ++j) vr[j] = drow[j * 64 + lane];

    unsigned lo = 0x007FFFFFu;  // key(-inf): cnt_gt >= 20
    unsigned hi = 0xFF800000u;  // key(+inf): cnt_gt == 0 < 20
#pragma unroll 1
    while (hi - lo > 1u) {
        unsigned mid = lo + ((hi - lo) >> 1);
        float tm = key2f(mid);
        int c = 0;
#pragma unroll
        for (int j = 0; j < 16; ++j) c += __popcll(__ballot(vr[j] > tm));
        if (c < KNN) hi = mid; else lo = mid;
    }
    float t = key2f(hi);  // V20 = 20th largest value

    int* outp = idxb + (size_t)gw * KNN;
    unsigned long long mylow = (1ull << lane) - 1ull;
    int base = 0;
#pragma unroll
    for (int j = 0; j < 16; ++j) {
        unsigned long long bmask = __ballot(vr[j] > t);
        if (vr[j] > t) outp[base + __popcll(bmask & mylow)] = j * 64 + lane;
        base += __popcll(bmask);
    }
#pragma unroll 1
    for (int j = 0; j < 16 && base < KNN; ++j) {
        unsigned long long bmask = __ballot(vr[j] == t);
        int pre = __popcll(bmask & mylow);
        if (vr[j] == t && base + pre < KNN) outp[base + pre] = j * 64 + lane;
        base += __popcll(bmask);
    }
}

// ---------- generic tiled GEMM: Y[r,o] = sum_k act(X[r*XS+k]) * W[k*OC+o] (+bias[(r>>10)*OC+o])
// X-staging via guarded float4 loads (XS%4==0; per-element k<K mask).
template<bool ACT, bool BIAS>
__global__ __launch_bounds__(256) void k_gemm(const float* __restrict__ X,
    const float* __restrict__ W, float* __restrict__ Y, int K, int OC, int XS,
    const float* __restrict__ scale, const float* __restrict__ shift,
    const float* __restrict__ bias)
{
    __shared__ float Xs[16][68];
    __shared__ float Ws[16][64];
    int r0 = blockIdx.x * 64, o0 = blockIdx.y * 64;
    int t = threadIdx.x;
    int tx = t & 15, ty = t >> 4;
    float acc[4][4] = {};
    for (int k0 = 0; k0 < K; k0 += 16) {
        __syncthreads();
        {
            int row = t >> 2, kb = (t & 3) * 4;
            float4 xv = make_float4(0.f, 0.f, 0.f, 0.f);
            if (k0 + kb < XS) xv = *(const float4*)&X[(size_t)(r0 + row) * XS + k0 + kb];
            float vv[4] = {xv.x, xv.y, xv.z, xv.w};
#pragma unroll
            for (int u = 0; u < 4; ++u) {
                int k = k0 + kb + u;
                float v = 0.f;
                if (k < K) {
                    v = vv[u];
                    if (ACT) { float z = fmaf(v, scale[k], shift[k]); v = fmaxf(z, 0.2f * z); }
                }
                Xs[kb + u][row] = v;
            }
            int kw = t >> 4, ow = (t & 15) * 4;
            float4 wv = make_float4(0.f, 0.f, 0.f, 0.f);
            if (k0 + kw < K) wv = *(const float4*)&W[(size_t)(k0 + kw) * OC + o0 + ow];
            *(float4*)&Ws[kw][ow] = wv;
        }
        __syncthreads();
#pragma unroll
        for (int k = 0; k < 16; ++k) {
            float4 a = *(const float4*)&Xs[k][ty * 4];
            float4 bb = *(const float4*)&Ws[k][tx * 4];
            float av[4] = {a.x, a.y, a.z, a.w};
            float bvv[4] = {bb.x, bb.y, bb.z, bb.w};
#pragma unroll
            for (int i = 0; i < 4; ++i)
#pragma unroll
                for (int j = 0; j < 4; ++j)
                    acc[i][j] = fmaf(av[i], bvv[j], acc[i][j]);
        }
    }
#pragma unroll
    for (int i = 0; i < 4; ++i) {
        int r = r0 + ty * 4 + i;
        float4 o4;
        float* po = (float*)&o4;
#pragma unroll
        for (int j = 0; j < 4; ++j) {
            float v = acc[i][j];
            if (BIAS) v += bias[(size_t)(r >> 10) * OC + o0 + tx * 4 + j];
            po[j] = v;
        }
        *(float4*)&Y[(size_t)r * OC + o0 + tx * 4] = o4;
    }
}

// ---------- gather neighbors, max over k, per-block BN partials (deterministic).
template<int O>
__global__ __launch_bounds__(256) void k_gather(const float* __restrict__ Z,
    const int* __restrict__ idxb, float* __restrict__ xo,
    float* __restrict__ part_s, float* __restrict__ part_q)
{
    constexpr int OL = O / 64;
    __shared__ float rs[4][O], rq[4][O];
    int b = blockIdx.y, nt = blockIdx.x;
    int t = threadIdx.x, lane = t & 63, w = t >> 6;
    float ps[OL] = {}, pq[OL] = {};
    for (int i = 0; i < 4; ++i) {
        int n = nt * 16 + w * 4 + i;
        size_t r = (size_t)b * NN + n;
        float zd[OL], ym[OL];
#pragma unroll
        for (int j = 0; j < OL; ++j) {
            int o = lane + j * 64;
            zd[j] = Z[r * (2 * O) + O + o] - Z[r * (2 * O) + o];
            ym[j] = -3.4e38f;
        }
        int midx[KNN];
        {
            const int4* ip = (const int4*)&idxb[r * KNN];
#pragma unroll
            for (int q = 0; q < 5; ++q) {
                int4 t4 = ip[q];
                midx[4 * q + 0] = t4.x; midx[4 * q + 1] = t4.y;
                midx[4 * q + 2] = t4.z; midx[4 * q + 3] = t4.w;
            }
        }
#pragma unroll
        for (int k = 0; k < KNN; ++k) {
            size_t rm = (size_t)b * NN + midx[k];
#pragma unroll
            for (int j = 0; j < OL; ++j) {
                float y = Z[rm * (2 * O) + lane + j * 64] + zd[j];
                ym[j] = fmaxf(ym[j], y);
                ps[j] += y; pq[j] = fmaf(y, y, pq[j]);
            }
        }
#pragma unroll
        for (int j = 0; j < OL; ++j) xo[r * O + lane + j * 64] = ym[j];
    }
#pragma unroll
    for (int j = 0; j < OL; ++j) { rs[w][lane + j * 64] = ps[j]; rq[w][lane + j * 64] = pq[j]; }
    __syncthreads();
    if (w == 0) {
        int blk = blockIdx.y * 64 + blockIdx.x;  // 0..2047, fixed slot per block
#pragma unroll
        for (int j = 0; j < OL; ++j) {
            int o = lane + j * 64;
            part_s[(size_t)o * 2048 + blk] = rs[0][o] + rs[1][o] + rs[2][o] + rs[3][o];
            part_q[(size_t)o * 2048 + blk] = rq[0][o] + rq[1][o] + rq[2][o] + rq[3][o];
        }
    }
}

// ---------- deterministic BN finalize from fixed-slot partials (2048 slots)
__global__ void k_bnfin2(const float* __restrict__ part_s, const float* __restrict__ part_q,
                         const float* __restrict__ g, const float* __restrict__ bb,
                         float* __restrict__ scale, float* __restrict__ shift,
                         int OC, float invM, float eps)
{
    int o = blockIdx.x * blockDim.x + threadIdx.x;
    if (o >= OC) return;
    const float* ps = part_s + (size_t)o * 2048;
    const float* pq = part_q + (size_t)o * 2048;
    float s0 = 0.f, s1 = 0.f, s2 = 0.f, s3 = 0.f;
    float q0 = 0.f, q1 = 0.f, q2 = 0.f, q3 = 0.f;
    for (int i = 0; i < 2048; i += 4) {
        s0 += ps[i]; s1 += ps[i + 1]; s2 += ps[i + 2]; s3 += ps[i + 3];
        q0 += pq[i]; q1 += pq[i + 1]; q2 += pq[i + 2]; q3 += pq[i + 3];
    }
    float s = (s0 + s1) + (s2 + s3);
    float q = (q0 + q1) + (q2 + q3);
    float mu = s * invM;
    float var = q * invM - mu * mu;
    float sc = g[o] * rsqrtf(var + eps);
    scale[o] = sc; shift[o] = bb[o] - mu * sc;
}

// ---------- conv-chain BN finalize from fixed-slot partials (128 slots, deterministic)
__global__ void k_bnfin3(const float* __restrict__ part_s, const float* __restrict__ part_q,
                         const float* __restrict__ g, const float* __restrict__ bb,
                         float* __restrict__ scale, float* __restrict__ shift,
                         int OC, float invM, float eps)
{
    int o = blockIdx.x * blockDim.x + threadIdx.x;
    if (o >= OC) return;
    const float* ps = part_s + (size_t)o * 128;
    const float* pq = part_q + (size_t)o * 128;
    float s0 = 0.f, s1 = 0.f, s2 = 0.f, s3 = 0.f;
    float q0 = 0.f, q1 = 0.f, q2 = 0.f, q3 = 0.f;
    for (int i = 0; i < 128; i += 4) {
        s0 += ps[i]; s1 += ps[i + 1]; s2 += ps[i + 2]; s3 += ps[i + 3];
        q0 += pq[i]; q1 += pq[i + 1]; q2 += pq[i + 2]; q3 += pq[i + 3];
    }
    float s = (s0 + s1) + (s2 + s3);
    float q = (q0 + q1) + (q2 + q3);
    float mu = s * invM;
    float var = q * invM - mu * mu;
    float sc = g[o] * rsqrtf(var + eps);
    scale[o] = sc; shift[o] = bb[o] - mu * sc;
}

// ---------- elementwise BN apply + lrelu (in place)
__global__ void k_bnapply(float* __restrict__ x, const float* __restrict__ scale,
                          const float* __restrict__ shift, int total, int O)
{
    int i = blockIdx.x * 256 + threadIdx.x;
    if (i >= total) return;
    int o = i & (O - 1);
    x[i] = lrelu(fmaf(x[i], scale[o], shift[o]));
}

// ---------- BN apply + lrelu + row-norm for O=64 tensors (xt1/xt2), float4.
__global__ __launch_bounds__(256) void k_bnapply_rn(float* __restrict__ x,
    const float* __restrict__ scale, const float* __restrict__ shift,
    float* __restrict__ xx)
{
    __shared__ float red[16][17];
    int t = threadIdx.x;
    int i4 = blockIdx.x * 256 + t;       // quad index; row = i4>>4 (block-aligned)
    int q = t & 15, lrow = t >> 4;
    float4 v = ((float4*)x)[i4];
    int o = q * 4;
    v.x = lrelu(fmaf(v.x, scale[o + 0], shift[o + 0]));
    v.y = lrelu(fmaf(v.y, scale[o + 1], shift[o + 1]));
    v.z = lrelu(fmaf(v.z, scale[o + 2], shift[o + 2]));
    v.w = lrelu(fmaf(v.w, scale[o + 3], shift[o + 3]));
    ((float4*)x)[i4] = v;
    float part = fmaf(v.w, v.w, fmaf(v.z, v.z, fmaf(v.y, v.y, v.x * v.x)));
    red[lrow][q] = part;
    __syncthreads();
    if (t < 16) {
        float s = 0.f;
#pragma unroll
        for (int j = 0; j < 16; ++j) s += red[t][j];
        xx[blockIdx.x * 16 + t] = s;
    }
}

// ---------- concat x1|x2|x3 -> fcat (B*N, 256)
__global__ void k_concat(const float* __restrict__ x1, const float* __restrict__ x2,
                         const float* __restrict__ x3, float* __restrict__ f)
{
    int i = blockIdx.x * 256 + threadIdx.x;
    if (i >= RTOT * 256) return;
    int r = i >> 8, c = i & 255;
    float v;
    if (c < 64) v = x1[(size_t)r * 64 + c];
    else if (c < 128) v = x2[(size_t)r * 64 + c - 64];
    else v = x3[(size_t)r * 128 + c - 128];
    f[(size_t)i] = v;
}

// ---------- LayerNorm stats per b over (N,40) of h (stride 64)
__global__ __launch_bounds__(256) void k_lnstats(const float* __restrict__ h, float* __restrict__ st)
{
    __shared__ float rsm[256], rqm[256];
    int b = blockIdx.x, t = threadIdx.x;
    float s = 0.f, q = 0.f;
    for (int i = t; i < 40960; i += 256) {
        int n = i / 40, o = i - n * 40;
        float v = h[((size_t)b * NN + n) * 64 + o];
        s += v; q = fmaf(v, v, q);
    }
    rsm[t] = s; rqm[t] = q; __syncthreads();
    for (int off = 128; off; off >>= 1) {
        if (t < off) { rsm[t] += rsm[t + off]; rqm[t] += rqm[t + off]; }
        __syncthreads();
    }
    if (t == 0) {
        float mu = rsm[0] / 40960.f;
        float var = rqm[0] / 40960.f - mu * mu;
        st[2 * b] = mu; st[2 * b + 1] = rsqrtf(var + 1e-6f);
    }
}

// ---------- LayerNorm apply + relu (in place on h -> encoder)
__global__ void k_lnapply(float* __restrict__ h, const float* __restrict__ lnw,
                          const float* __restrict__ lnb, const float* __restrict__ st)
{
    int i = blockIdx.x * 256 + threadIdx.x;
    if (i >= NB * NN * 40) return;
    int b = i / 40960, rem = i - b * 40960, n = rem / 40, o = rem - n * 40;
    float mu = st[2 * b], rstd = st[2 * b + 1];
    size_t a = ((size_t)b * NN + n) * 64 + o;
    float v = fmaf((h[a] - mu) * rstd, lnw[n * 40 + o], lnb[n * 40 + o]);
    h[a] = fmaxf(v, 0.f);
}

// ---------- u_hat fused with s1 = sum_p u. ONE wave per block, grid (64 pc, 40 l).
__global__ __launch_bounds__(64) void k_uhat(const float* __restrict__ enc,
    const float* __restrict__ caps, float* __restrict__ U, float* __restrict__ pbu)
{
    __shared__ float clt[40 * 68];
    int pc = blockIdx.x, l = blockIdx.y;
    int lane = threadIdx.x;
    int vg = lane & 7, bg = lane >> 3;
    int v0 = vg * 8, b0 = bg * 4;
    float spart[4][8] = {};
#pragma unroll 1
    for (int pi = 0; pi < 16; ++pi) {
        int p = pc * 16 + pi;
        const float4* cp4 = (const float4*)(caps + ((size_t)l * NN + p) * 2560);
#pragma unroll
        for (int k = 0; k < 10; ++k) {
            int i4 = lane + k * 64;        // 0..639
            float4 cv = cp4[i4];
            int e0 = i4 * 4;
            int v = e0 / 40;
            int d0 = e0 - v * 40;
            clt[(d0 + 0) * 68 + v] = cv.x;
            clt[(d0 + 1) * 68 + v] = cv.y;
            clt[(d0 + 2) * 68 + v] = cv.z;
            clt[(d0 + 3) * 68 + v] = cv.w;
        }
        float acc[4][8] = {};
#pragma unroll
        for (int d4 = 0; d4 < 10; ++d4) {
            float4 e4[4];
#pragma unroll
            for (int i = 0; i < 4; ++i)
                e4[i] = *(const float4*)&enc[((size_t)(b0 + i) * NN + p) * 64 + d4 * 4];
#pragma unroll
            for (int dd = 0; dd < 4; ++dd) {
                int d = d4 * 4 + dd;
                float4 c0 = *(const float4*)&clt[d * 68 + v0];
                float4 c1 = *(const float4*)&clt[d * 68 + v0 + 4];
                float cv[8] = {c0.x, c0.y, c0.z, c0.w, c1.x, c1.y, c1.z, c1.w};
#pragma unroll
                for (int i = 0; i < 4; ++i) {
                    float e = ((const float*)&e4[i])[dd];
#pragma unroll
                    for (int j = 0; j < 8; ++j)
                        acc[i][j] = fmaf(e, cv[j], acc[i][j]);
                }
            }
        }
#pragma unroll
        for (int i = 0; i < 4; ++i) {
            float* up = &U[((size_t)(b0 + i) * NN + p) * 2560 + l * 64 + v0];
            float4 o0 = make_float4(acc[i][0], acc[i][1], acc[i][2], acc[i][3]);
            float4 o1 = make_float4(acc[i][4], acc[i][5], acc[i][6], acc[i][7]);
            *(float4*)up = o0;
            *(float4*)(up + 4) = o1;
#pragma unroll
            for (int j = 0; j < 8; ++j) spart[i][j] += acc[i][j];
        }
    }
    float* pb = pbu + (size_t)pc * 81920;
#pragma unroll
    for (int i = 0; i < 4; ++i) {
        float4 s0 = make_float4(spart[i][0], spart[i][1], spart[i][2], spart[i][3]);
        float4 s1 = make_float4(spart[i][4], spart[i][5], spart[i][6], spart[i][7]);
        float* dst = &pb[(size_t)(b0 + i) * 2560 + l * 64 + v0];
        *(float4*)dst = s0;
        *(float4*)(dst + 4) = s1;
    }
}

// ---------- routing pass, float4-vectorized U stream (round-14 known-good form:
// eo[] kept, launch_bounds (256,4); register budget ~110 VGPR, no spills).
template<int MODE>
__global__ __launch_bounds__(256, 4) void k_route(const float* __restrict__ U,
    const float* __restrict__ vprev, const float* __restrict__ bin,
    float* __restrict__ bout, float* __restrict__ pbuf)
{
    __shared__ float vl[2560];
    __shared__ float red[4][1280];
    int b = blockIdx.x, pc = blockIdx.y;
    int t = threadIdx.x, lane = t & 63, w = t >> 6;
    for (int i = t; i < 2560; i += 256) vl[i] = vprev[(size_t)b * 2560 + i];
    __syncthreads();
    float4 acc[10];
#pragma unroll
    for (int it = 0; it < 10; ++it) acc[it] = make_float4(0.f, 0.f, 0.f, 0.f);
    int lgrp = lane >> 4;
#pragma unroll 1
    for (int pi = 0; pi < 8; ++pi) {
        int p = pc * 32 + w * 8 + pi;
        const float4* up4 = (const float4*)(U + ((size_t)b * NN + p) * 2560);
        float4 u[10];
#pragma unroll
        for (int it = 0; it < 10; ++it) u[it] = up4[it * 64 + lane];
        float pd[10];
#pragma unroll
        for (int it = 0; it < 10; ++it) {
            float4 vv = *(const float4*)&vl[it * 256 + lane * 4];
            float s = u[it].x * vv.x;
            s = fmaf(u[it].y, vv.y, s);
            s = fmaf(u[it].z, vv.z, s);
            s = fmaf(u[it].w, vv.w, s);
            s += __shfl_xor(s, 1, 64);
            s += __shfl_xor(s, 2, 64);
            s += __shfl_xor(s, 4, 64);
            s += __shfl_xor(s, 8, 64);
            pd[it] = s;
        }
        if (MODE == 1) {
            if ((lane & 15) == 0) {
#pragma unroll
                for (int it = 0; it < 10; ++it)
                    bout[((size_t)b * 40 + it * 4 + lgrp) * NN + p] = pd[it];
            }
        } else {
#pragma unroll
            for (int it = 0; it < 10; ++it)
                pd[it] += bin[((size_t)b * 40 + it * 4 + lgrp) * NN + p];
        }
        float mx = -3.4e38f;
#pragma unroll
        for (int it = 0; it < 10; ++it) {
            float m = pd[it];
            m = fmaxf(m, __shfl_xor(m, 16, 64));
            m = fmaxf(m, __shfl_xor(m, 32, 64));
            mx = fmaxf(mx, m);
        }
        float eo[10]; float se = 0.f;
#pragma unroll
        for (int it = 0; it < 10; ++it) {
            float e = expf(pd[it] - mx);
            eo[it] = e;
            float sg = e;
            sg += __shfl_xor(sg, 16, 64);
            sg += __shfl_xor(sg, 32, 64);
            se += sg;
        }
        float inv = 1.f / se;
#pragma unroll
        for (int it = 0; it < 10; ++it) {
            float wgt = eo[it] * inv;
            acc[it].x = fmaf(wgt, u[it].x, acc[it].x);
            acc[it].y = fmaf(wgt, u[it].y, acc[it].y);
            acc[it].z = fmaf(wgt, u[it].z, acc[it].z);
            acc[it].w = fmaf(wgt, u[it].w, acc[it].w);
        }
    }
    float* pb = pbuf + ((size_t)pc * NB + b) * 2560;
#pragma unroll 1
    for (int h = 0; h < 2; ++h) {
        __syncthreads();
#pragma unroll
        for (int it = 0; it < 5; ++it)
            *(float4*)&red[w][it * 256 + lane * 4] = acc[h * 5 + it];
        __syncthreads();
        if (w == 0) {
#pragma unroll
            for (int it = 0; it < 5; ++it) {
                int idx = it * 256 + lane * 4;
                float4 a0 = *(const float4*)&red[0][idx];
                float4 a1 = *(const float4*)&red[1][idx];
                float4 a2 = *(const float4*)&red[2][idx];
                float4 a3 = *(const float4*)&red[3][idx];
                float4 o = make_float4((a0.x + a1.x) + (a2.x + a3.x),
                                       (a0.y + a1.y) + (a2.y + a3.y),
                                       (a0.z + a1.z) + (a2.z + a3.z),
                                       (a0.w + a1.w) + (a2.w + a3.w));
                *(float4*)&pb[h * 1280 + idx] = o;
            }
        }
    }
}

// ---------- fused: reduce partials over NCH chunks + squash -> vb. Deterministic.
template<int NCH>
__global__ __launch_bounds__(256) void k_sredsq(const float* __restrict__ pbuf,
    float* __restrict__ vout, float premul)
{
    __shared__ float red[16][17];
    __shared__ float fac[16];
    int t = threadIdx.x;
    int i4 = blockIdx.x * 256 + t;       // quad index over NB*40*16 = 20480
    int q = t & 15, lrow = t >> 4;
    const float4* pb4 = (const float4*)pbuf;
    float4 s = make_float4(0.f, 0.f, 0.f, 0.f);
#pragma unroll 4
    for (int pc = 0; pc < NCH; ++pc) {
        float4 v = pb4[(size_t)pc * (NB * 640) + i4];
        s.x += v.x; s.y += v.y; s.z += v.z; s.w += v.w;
    }
    s.x *= premul; s.y *= premul; s.z *= premul; s.w *= premul;
    float part = fmaf(s.w, s.w, fmaf(s.z, s.z, fmaf(s.y, s.y, s.x * s.x)));
    red[lrow][q] = part;
    __syncthreads();
    if (t < 16) {
        float sn = 0.f;
#pragma unroll
        for (int j = 0; j < 16; ++j) sn += red[t][j];
        fac[t] = sn / ((1.f + sn) * sqrtf(sn));
    }
    __syncthreads();
    float f = fac[lrow];
    ((float4*)vout)[i4] = make_float4(s.x * f, s.y * f, s.z * f, s.w * f);
}

// ---------- emb = enc @ latent, max over v
__global__ __launch_bounds__(256) void k_emb(const float* __restrict__ enc,
    const float* __restrict__ lat, float* __restrict__ embm)
{
    __shared__ float latl[2560];
    int b = blockIdx.x, pt = blockIdx.y;
    int t = threadIdx.x, lane = t & 63, w = t >> 6;
    for (int i = t; i < 2560; i += 256) latl[i] = lat[(size_t)b * 2560 + i];
    __syncthreads();
    for (int i = 0; i < 32; ++i) {
        int p = pt * 128 + w * 32 + i;
        const float* ep = enc + ((size_t)b * NN + p) * 64;
        float acc = 0.f;
#pragma unroll
        for (int d = 0; d < 40; ++d) acc = fmaf(ep[d], latl[d * 64 + lane], acc);
        float mx = acc;
#pragma unroll
        for (int s = 32; s; s >>= 1) mx = fmaxf(mx, __shfl_xor(mx, s, 64));
        if (lane == 0) embm[(size_t)b * NN + p] = mx;
    }
}

// ---------- base2 with integrated lab
__global__ __launch_bounds__(256) void k_base2(const float* __restrict__ em,
    const float* __restrict__ lin, const float* __restrict__ cw1,
    const float* __restrict__ cg1, const float* __restrict__ cb1,
    const float* __restrict__ cw2, float* __restrict__ base)
{
    __shared__ float eml[1024];
    __shared__ float lbl[64];
    int b = blockIdx.x, t = threadIdx.x;
    for (int i = t; i < 1024; i += 256) eml[i] = em[(size_t)b * NN + i];
    if (t < 64) {
        int o = t;
        float ys[32]; float s = 0.f, q = 0.f;
#pragma unroll
        for (int bb = 0; bb < 32; ++bb) {
            float y = 0.f;
#pragma unroll
            for (int c = 0; c < 16; ++c) y = fmaf(lin[bb * 16 + c], cw1[o * 16 + c], y);
            ys[bb] = y; s += y; q = fmaf(y, y, q);
        }
        float mu = s / 32.f, var = q / 32.f - mu * mu;
        float sc = cg1[o] * rsqrtf(var + 1e-5f);
        float sh = cb1[o] - mu * sc;
        lbl[o] = lrelu(fmaf(ys[b], sc, sh));
    }
    __syncthreads();
    const float* wr = cw2 + (size_t)t * 1128;
    float acc = 0.f;
    for (int c = 0; c < 1024; ++c) acc = fmaf(wr[c], eml[c], acc);
#pragma unroll
    for (int c = 0; c < 64; ++c) acc = fmaf(wr[1024 + c], lbl[c], acc);
    base[b * 256 + t] = acc;
}

// ---------- column stats over rows, fixed-slot partials (deterministic)
__global__ __launch_bounds__(256) void k_colstats2(const float* __restrict__ Y,
    float* __restrict__ part_s, float* __restrict__ part_q, int OC)
{
    __shared__ float rs[4][64], rq[4][64];
    int chunk = blockIdx.x, o0 = blockIdx.y * 64;
    int t = threadIdx.x, lane = t & 63, w = t >> 6;
    int o = o0 + lane;
    float s = 0.f, q = 0.f;
    for (int j = 0; j < 64; ++j) {
        int r = chunk * 256 + w * 64 + j;
        float v = Y[(size_t)r * OC + o];
        s += v; q = fmaf(v, v, q);
    }
    rs[w][lane] = s; rq[w][lane] = q;
    __syncthreads();
    if (w == 0) {
        part_s[(size_t)o * 128 + chunk] = rs[0][lane] + rs[1][lane] + rs[2][lane] + rs[3][lane];
        part_q[(size_t)o * 128 + chunk] = rq[0][lane] + rq[1][lane] + rq[2][lane] + rq[3][lane];
    }
}

// ---------- final: BN+lrelu+transpose to out (B,50,N)
__global__ void k_out(const float* __restrict__ Y, const float* __restrict__ scale,
                      const float* __restrict__ shift, float* __restrict__ out)
{
    int i = blockIdx.x * 256 + threadIdx.x;
    if (i >= NB * 50 * NN) return;
    int n = i & 1023, rest = i >> 10;
    int o = rest % 50, b = rest / 50;
    float y = Y[((size_t)b * NN + n) * 64 + o];
    out[i] = lrelu(fmaf(y, scale[o], shift[o]));
}

extern "C" void kernel_launch(void* const* d_in, const int* in_sizes, int n_in,
                              void* d_out, int out_size, void* d_ws, size_t ws_size,
                              hipStream_t stream)
{
    const float* data = (const float*)d_in[0];
    const float* lin  = (const float*)d_in[1];
    const float* dw1  = (const float*)d_in[2];
    const float* dg1  = (const float*)d_in[3];
    const float* db1  = (const float*)d_in[4];
    const float* dw2  = (const float*)d_in[5];
    const float* dg2  = (const float*)d_in[6];
    const float* db2  = (const float*)d_in[7];
    const float* dw3  = (const float*)d_in[8];
    const float* dg3  = (const float*)d_in[9];
    const float* db3  = (const float*)d_in[10];
    const float* lw   = (const float*)d_in[11];
    const float* lnw  = (const float*)d_in[12];
    const float* lnb  = (const float*)d_in[13];
    const float* caps = (const float*)d_in[14];
    const float* cw1  = (const float*)d_in[15];
    const float* cg1  = (const float*)d_in[16];
    const float* cb1  = (const float*)d_in[17];
    const float* cw2  = (const float*)d_in[18];
    const float* cg2  = (const float*)d_in[19];
    const float* cb2  = (const float*)d_in[20];
    const float* cw3  = (const float*)d_in[21];
    const float* cw4  = (const float*)d_in[22];
    const float* cg4  = (const float*)d_in[23];
    const float* cb4  = (const float*)d_in[24];
    const float* cw5  = (const float*)d_in[25];
    const float* cg5  = (const float*)d_in[26];
    const float* cb5  = (const float*)d_in[27];
    float* out = (float*)d_out;
    float* ws = (float*)d_ws;

    float* big  = ws + O_BIG;
    float* xt0  = ws + O_XT0;
    float* xt1  = ws + O_XT1;
    float* xt2  = ws + O_XT2;
    float* xt3  = ws + O_XT3;
    float* xxp  = ws + O_XX;
    int*   idxb = (int*)(ws + O_IDX);
    float* wc1  = ws + O_WC1;
    float* wc2  = ws + O_WC2;
    float* wc3  = ws + O_WC3;
    float* lwt  = ws + O_LWT;
    float* c2t  = ws + O_C2T;
    float* c3t  = ws + O_C3T;
    float* c4t  = ws + O_C4T;
    float* c5t  = ws + O_C5T;
    float* hbuf = ws + O_H;
    float* lnst = ws + O_LNST;
    float* scl  = ws + O_SCL;
    float* shf  = ws + O_SHF;
    float* vb   = ws + O_VB;
    float* bij  = ws + O_BIJ;
    float* embm = ws + O_EMB;
    float* basep= ws + O_BASE;
    float* psP  = ws + O_PS;        // partials (alias bij; disjoint lifetimes)
    float* pqP  = ws + O_PQ;
    float* pbuf = ws + O_PB;        // routing partials (alias xt1/xt2; dead after concat)
    float* pbu  = ws + O_PBU;       // uhat s1 partials (same region, used before routing pbuf)
    float* Dbuf = big;              // distances, then Z, then fcat/u_hat/ybufs
    float* Z    = big;
    float* U    = big;
    float* yb1  = big;
    float* yb2  = big + 8388608;

    // ---- weight prep (single kernel) + data transpose w/ fused norm
    k_wtall<<<618, 256, 0, stream>>>(dw1, dw2, dw3, lw, cw2, cw3, cw4, cw5,
                                     wc1, wc2, wc3, lwt, c2t, c3t, c4t, c5t);
    k_data_t<<<128, 256, 0, stream>>>(data, xt0, xxp);

    // ---- stage 1 (C=3 -> O=64)
    k_dist<4><<<dim3(16, 16, 32), 256, 0, stream>>>(xt0, xxp, Dbuf);
    k_sel<<<8192, 256, 0, stream>>>(Dbuf, idxb);
    k_gemm<false, false><<<dim3(512, 2), 256, 0, stream>>>(xt0, wc1, Z, 3, 128, 4, nullptr, nullptr, nullptr);
    k_gather<64><<<dim3(64, 32), 256, 0, stream>>>(Z, idxb, xt1, psP, pqP);
    k_bnfin2<<<1, 64, 0, stream>>>(psP, pqP, dg1, db1, scl, shf, 64, 1.f / 655360.f, 1e-5f);
    k_bnapply_rn<<<2048, 256, 0, stream>>>(xt1, scl, shf, xxp);

    // ---- stage 2 (C=64 -> O=64)
    k_dist<64><<<dim3(16, 16, 32), 256, 0, stream>>>(xt1, xxp, Dbuf);
    k_sel<<<8192, 256, 0, stream>>>(Dbuf, idxb);
    k_gemm<false, false><<<dim3(512, 2), 256, 0, stream>>>(xt1, wc2, Z, 64, 128, 64, nullptr, nullptr, nullptr);
    k_gather<64><<<dim3(64, 32), 256, 0, stream>>>(Z, idxb, xt2, psP, pqP);
    k_bnfin2<<<1, 64, 0, stream>>>(psP, pqP, dg2, db2, scl, shf, 64, 1.f / 655360.f, 1e-5f);
    k_bnapply_rn<<<2048, 256, 0, stream>>>(xt2, scl, shf, xxp);

    // ---- stage 3 (C=64 -> O=128)
    k_dist<64><<<dim3(16, 16, 32), 256, 0, stream>>>(xt2, xxp, Dbuf);
    k_sel<<<8192, 256, 0, stream>>>(Dbuf, idxb);
    k_gemm<false, false><<<dim3(512, 4), 256, 0, stream>>>(xt2, wc3, Z, 64, 256, 64, nullptr, nullptr, nullptr);
    k_gather<128><<<dim3(64, 32), 256, 0, stream>>>(Z, idxb, xt3, psP, pqP);
    k_bnfin2<<<1, 128, 0, stream>>>(psP, pqP, dg3, db3, scl, shf, 128, 1.f / 655360.f, 1e-5f);
    k_bnapply<<<16384, 256, 0, stream>>>(xt3, scl, shf, RTOT * 128, 128);

    // ---- feat concat, linear, LayerNorm (-> encoder in hbuf)
    k_concat<<<32768, 256, 0, stream>>>(xt1, xt2, xt3, big);
    k_gemm<false, false><<<dim3(512, 1), 256, 0, stream>>>(big, lwt, hbuf, 256, 64, 256, nullptr, nullptr, nullptr);
    k_lnstats<<<32, 256, 0, stream>>>(hbuf, lnst);
    k_lnapply<<<5120, 256, 0, stream>>>(hbuf, lnw, lnb, lnst);

    // ---- capsules (xt1..xt3 now dead -> pbu/pbuf alias them)
    k_uhat<<<dim3(64, 40), 64, 0, stream>>>(hbuf, caps, U, pbu);
    k_sredsq<64><<<80, 256, 0, stream>>>(pbu, vb, 1.f / 40.f);
    k_route<1><<<dim3(32, 32), 256, 0, stream>>>(U, vb, nullptr, bij, pbuf);
    k_sredsq<32><<<80, 256, 0, stream>>>(pbuf, vb, 1.f);
    k_route<2><<<dim3(32, 32), 256, 0, stream>>>(U, vb, bij, nullptr, pbuf);
    k_sredsq<32><<<80, 256, 0, stream>>>(pbuf, vb, 1.f);

    // ---- emb, base2 (lab integrated)
    k_emb<<<dim3(32, 8), 256, 0, stream>>>(hbuf, vb, embm);
    k_base2<<<32, 256, 0, stream>>>(embm, lin, cw1, cg1, cb1, cw2, basep);

    // ---- conv chain (deterministic fixed-slot BN partials)
    k_gemm<false, true><<<dim3(512, 4), 256, 0, stream>>>(hbuf, c2t, yb1, 40, 256, 64, nullptr, nullptr, basep);
    k_colstats2<<<dim3(128, 4), 256, 0, stream>>>(yb1, psP, pqP, 256);
    k_bnfin3<<<1, 256, 0, stream>>>(psP, pqP, cg2, cb2, scl, shf, 256, 1.f / 32768.f, 1e-5f);

    k_gemm<true, false><<<dim3(512, 4), 256, 0, stream>>>(yb1, c3t, yb2, 256, 256, 256, scl, shf, nullptr);
    k_colstats2<<<dim3(128, 4), 256, 0, stream>>>(yb2, psP, pqP, 256);
    k_bnfin3<<<1, 256, 0, stream>>>(psP, pqP, cg2, cb2, scl, shf, 256, 1.f / 32768.f, 1e-5f);

    k_gemm<true, false><<<dim3(512, 2), 256, 0, stream>>>(yb2, c4t, yb1, 256, 128, 256, scl, shf, nullptr);
    k_colstats2<<<dim3(128, 2), 256, 0, stream>>>(yb1, psP, pqP, 128);
    k_bnfin3<<<1, 256, 0, stream>>>(psP, pqP, cg4, cb4, scl, shf, 128, 1.f / 32768.f, 1e-5f);

    k_gemm<true, false><<<dim3(512, 1), 256, 0, stream>>>(yb1, c5t, yb2, 128, 64, 128, scl, shf, nullptr);
    k_colstats2<<<dim3(128, 1), 256, 0, stream>>>(yb2, psP, pqP, 64);
    k_bnfin3<<<1, 256, 0, stream>>>(psP, pqP, cg5, cb5, scl, shf, 50, 1.f / 32768.f, 1e-5f);

    k_out<<<6400, 256, 0, stream>>>(yb2, scl, shf, out);
}

// Round 17
// 1527.806 us; speedup vs baseline: 1.1985x; 1.0661x over previous
//
#include <hip/hip_runtime.h>
#include <math.h>

constexpr int NB = 32, NN = 1024, KNN = 20;
constexpr int RTOT = NB * NN; // 32768

// ---------------- workspace offsets (in floats) ----------------
constexpr size_t SZ_BIG = (size_t)NB * NN * 40 * 64;      // 83,886,080 (u_hat(bf16) / D / Z / fcat / ybufs)
constexpr size_t O_BIG  = 0;
constexpr size_t O_XT0  = O_BIG + SZ_BIG;                  // (B,N,4) data transposed
constexpr size_t O_XT1  = O_XT0 + (size_t)RTOT * 4;        // (B,N,64)
constexpr size_t O_XT2  = O_XT1 + (size_t)RTOT * 64;       // (B,N,64)
constexpr size_t O_XT3  = O_XT2 + (size_t)RTOT * 64;       // (B,N,128)
constexpr size_t O_XX   = O_XT3 + (size_t)RTOT * 128;      // row norms
constexpr size_t O_IDX  = O_XX + RTOT;                     // int (B,N,20)
constexpr size_t O_WC1  = O_IDX + (size_t)RTOT * KNN;      // 4x128
constexpr size_t O_WC2  = O_WC1 + 512;                     // 64x128
constexpr size_t O_WC3  = O_WC2 + 8192;                    // 64x256
constexpr size_t O_LWT  = O_WC3 + 16384;                   // 256x64
constexpr size_t O_C2T  = O_LWT + 16384;                   // 40x256
constexpr size_t O_C3T  = O_C2T + 10240;                   // 256x256
constexpr size_t O_C4T  = O_C3T + 65536;                   // 256x128
constexpr size_t O_C5T  = O_C4T + 32768;                   // 128x64
constexpr size_t O_H    = O_C5T + 8192;                    // (B,N,64) h / encoder
constexpr size_t O_LNST = O_H + (size_t)RTOT * 64;         // 2 per b
constexpr size_t O_BSUM = O_LNST + 64;
constexpr size_t O_BSQ  = O_BSUM + 256;
constexpr size_t O_SCL  = O_BSQ + 256;
constexpr size_t O_SHF  = O_SCL + 256;
constexpr size_t O_SACC = O_SHF + 256;                     // (unused)
constexpr size_t O_VB   = O_SACC + 81920;                  // (B,40,64)
constexpr size_t O_BIJ  = O_VB + 81920;                    // (B,40,1024) routing b; ALSO partials
constexpr size_t O_EMB  = O_BIJ + (size_t)NB * 40 * NN;    // (B,N)
constexpr size_t O_LAB  = O_EMB + RTOT;                    // (unused)
constexpr size_t O_BASE = O_LAB + 2048;                    // (B,256)
// BN partials alias bij (lifetimes disjoint)
constexpr size_t O_PS   = O_BIJ;
constexpr size_t O_PQ   = O_BIJ + 262144;
// partial buffers alias xt1..xt3 (dead after k_concat):
constexpr size_t O_PB   = O_XT1;   // routing partials: 32*81920 floats
constexpr size_t O_PBU  = O_XT1;   // uhat s-sum partials: 64*81920 floats

__device__ __forceinline__ float lrelu(float z) { return fmaxf(z, 0.2f * z); }

// sortable-uint key <-> float (ascending key == ascending float)
__device__ __forceinline__ float key2f(unsigned u)
{
    unsigned b = (u & 0x80000000u) ? (u ^ 0x80000000u) : ~u;
    return __uint_as_float(b);
}

// pack two floats to bf16 pair (RNE), a in low 16, b in high 16
__device__ __forceinline__ unsigned bfpack(float a, float b)
{
    unsigned ua = __float_as_uint(a); unsigned ub = __float_as_uint(b);
    ua += 0x7FFFu + ((ua >> 16) & 1u);
    ub += 0x7FFFu + ((ub >> 16) & 1u);
    return (ua >> 16) | (ub & 0xFFFF0000u);
}
__device__ __forceinline__ float bflo(unsigned u) { return __uint_as_float(u << 16); }
__device__ __forceinline__ float bfhi(unsigned u) { return __uint_as_float(u & 0xFFFF0000u); }

// ---------- all weight transposes in ONE kernel (blockIdx-range dispatch)
__device__ __forceinline__ void wt_do(const float* __restrict__ src, float* __restrict__ dst,
                                      int i, int K, int On, int SS, int coff, int DS, int ooff, int Oreal)
{
    if (i >= K * On) return;
    int c = i / On, o = i - c * On;
    dst[(size_t)c * DS + ooff + o] = (o < Oreal) ? src[(size_t)o * SS + coff + c] : 0.f;
}

__global__ __launch_bounds__(256) void k_wtall(
    const float* __restrict__ dw1, const float* __restrict__ dw2, const float* __restrict__ dw3,
    const float* __restrict__ lw,  const float* __restrict__ cw2, const float* __restrict__ cw3,
    const float* __restrict__ cw4, const float* __restrict__ cw5,
    float* __restrict__ wc1, float* __restrict__ wc2, float* __restrict__ wc3,
    float* __restrict__ lwt, float* __restrict__ c2t, float* __restrict__ c3t,
    float* __restrict__ c4t, float* __restrict__ c5t)
{
    int bid = blockIdx.x, t = threadIdx.x;
    if      (bid < 1)   wt_do(dw1, wc1, (bid - 0) * 256 + t,   3, 64, 6, 0, 128, 0, 64);
    else if (bid < 2)   wt_do(dw1, wc1, (bid - 1) * 256 + t,   3, 64, 6, 3, 128, 64, 64);
    else if (bid < 18)  wt_do(dw2, wc2, (bid - 2) * 256 + t,   64, 64, 128, 0, 128, 0, 64);
    else if (bid < 34)  wt_do(dw2, wc2, (bid - 18) * 256 + t,  64, 64, 128, 64, 128, 64, 64);
    else if (bid < 66)  wt_do(dw3, wc3, (bid - 34) * 256 + t,  64, 128, 128, 0, 256, 0, 128);
    else if (bid < 98)  wt_do(dw3, wc3, (bid - 66) * 256 + t,  64, 128, 128, 64, 256, 128, 128);
    else if (bid < 162) wt_do(lw,  lwt, (bid - 98) * 256 + t,  256, 64, 256, 0, 64, 0, 40);
    else if (bid < 202) wt_do(cw2, c2t, (bid - 162) * 256 + t, 40, 256, 1128, 1088, 256, 0, 256);
    else if (bid < 458) wt_do(cw3, c3t, (bid - 202) * 256 + t, 256, 256, 256, 0, 256, 0, 256);
    else if (bid < 586) wt_do(cw4, c4t, (bid - 458) * 256 + t, 256, 128, 256, 0, 128, 0, 128);
    else                wt_do(cw5, c5t, (bid - 586) * 256 + t, 128, 64, 128, 0, 64, 0, 50);
}

// ---------- data (B,3,N) -> xt0 (B,N,4), fused row-norm
__global__ void k_data_t(const float* __restrict__ d, float* __restrict__ xt,
                         float* __restrict__ xx)
{
    int i = blockIdx.x * 256 + threadIdx.x;
    if (i >= RTOT) return;
    int b = i >> 10, n = i & 1023;
    float s = 0.f;
#pragma unroll
    for (int c = 0; c < 3; ++c) {
        float v = d[((size_t)b * 3 + c) * NN + n];
        xt[(size_t)i * 4 + c] = v;
        s = fmaf(v, v, s);
    }
    xt[(size_t)i * 4 + 3] = 0.f;
    xx[i] = s;
}

// ---------- batched pairwise-score GEMM: D[b,r,m] = 2 * x_r . x_m - ||x_m||^2
template<int CS>
__global__ __launch_bounds__(256) void k_dist(const float* __restrict__ X,
    const float* __restrict__ xx, float* __restrict__ D)
{
    __shared__ float As[16][68];
    __shared__ float Bs[16][68];
    int b = blockIdx.z;
    int r0 = blockIdx.x * 64, m0 = blockIdx.y * 64;
    const float* Xb = X + (size_t)b * NN * CS;
    int t = threadIdx.x;
    int tx = t & 15, ty = t >> 4;
    float acc[4][4] = {};
    for (int k0 = 0; k0 < CS; k0 += 16) {
        __syncthreads();
        {
            int row = t >> 2, kb = (t & 3) * 4;
            float4 a4 = make_float4(0.f, 0.f, 0.f, 0.f);
            float4 b4 = make_float4(0.f, 0.f, 0.f, 0.f);
            if (k0 + kb < CS) {
                a4 = *(const float4*)&Xb[(size_t)(r0 + row) * CS + k0 + kb];
                b4 = *(const float4*)&Xb[(size_t)(m0 + row) * CS + k0 + kb];
            }
            As[kb + 0][row] = a4.x; As[kb + 1][row] = a4.y;
            As[kb + 2][row] = a4.z; As[kb + 3][row] = a4.w;
            Bs[kb + 0][row] = b4.x; Bs[kb + 1][row] = b4.y;
            Bs[kb + 2][row] = b4.z; Bs[kb + 3][row] = b4.w;
        }
        __syncthreads();
#pragma unroll
        for (int k = 0; k < 16; ++k) {
            float4 a = *(const float4*)&As[k][ty * 4];
            float4 bb = *(const float4*)&Bs[k][tx * 4];
            float av[4] = {a.x, a.y, a.z, a.w};
            float bv[4] = {bb.x, bb.y, bb.z, bb.w};
#pragma unroll
            for (int i = 0; i < 4; ++i)
#pragma unroll
                for (int j = 0; j < 4; ++j)
                    acc[i][j] = fmaf(av[i], bv[j], acc[i][j]);
        }
    }
    const float* xxb = xx + b * NN + m0 + tx * 4;
    float x0 = xxb[0], x1 = xxb[1], x2 = xxb[2], x3 = xxb[3];
#pragma unroll
    for (int i = 0; i < 4; ++i) {
        float4 o4 = make_float4(2.f * acc[i][0] - x0, 2.f * acc[i][1] - x1,
                                2.f * acc[i][2] - x2, 2.f * acc[i][3] - x3);
        *(float4*)&D[((size_t)b * NN + r0 + ty * 4 + i) * NN + m0 + tx * 4] = o4;
    }
}

// ---------- top-20 SET selection per row (downstream is order-invariant).
__global__ __launch_bounds__(256) void k_sel(const float* __restrict__ D,
                                             int* __restrict__ idxb)
{
    int gw = blockIdx.x * 4 + (threadIdx.x >> 6);
    int lane = threadIdx.x & 63;
    const float* drow = D + (size_t)gw * NN;
    float vr[16];
#pragma unroll
    for (int j = 0; j < 16; ++j) vr[j] = drow[j * 64 + lane];

    unsigned lo = 0x007FFFFFu;  // key(-inf): cnt_gt >= 20
    unsigned hi = 0xFF800000u;  // key(+inf): cnt_gt == 0 < 20
#pragma unroll 1
    while (hi - lo > 1u) {
        unsigned mid = lo + ((hi - lo) >> 1);
        float tm = key2f(mid);
        int c = 0;
#pragma unroll
        for (int j = 0; j < 16; ++j) c += __popcll(__ballot(vr[j] > tm));
        if (c < KNN) hi = mid; else lo = mid;
    }
    float t = key2f(hi);  // V20 = 20th largest value

    int* outp = idxb + (size_t)gw * KNN;
    unsigned long long mylow = (1ull << lane) - 1ull;
    int base = 0;
#pragma unroll
    for (int j = 0; j < 16; ++j) {
        unsigned long long bmask = __ballot(vr[j] > t);
        if (vr[j] > t) outp[base + __popcll(bmask & mylow)] = j * 64 + lane;
        base += __popcll(bmask);
    }
#pragma unroll 1
    for (int j = 0; j < 16 && base < KNN; ++j) {
        unsigned long long bmask = __ballot(vr[j] == t);
        int pre = __popcll(bmask & mylow);
        if (vr[j] == t && base + pre < KNN) outp[base + pre] = j * 64 + lane;
        base += __popcll(bmask);
    }
}

// ---------- generic tiled GEMM: Y[r,o] = sum_k act(X[r*XS+k]) * W[k*OC+o] (+bias)
template<bool ACT, bool BIAS>
__global__ __launch_bounds__(256) void k_gemm(const float* __restrict__ X,
    const float* __restrict__ W, float* __restrict__ Y, int K, int OC, int XS,
    const float* __restrict__ scale, const float* __restrict__ shift,
    const float* __restrict__ bias)
{
    __shared__ float Xs[16][68];
    __shared__ float Ws[16][64];
    int r0 = blockIdx.x * 64, o0 = blockIdx.y * 64;
    int t = threadIdx.x;
    int tx = t & 15, ty = t >> 4;
    float acc[4][4] = {};
    for (int k0 = 0; k0 < K; k0 += 16) {
        __syncthreads();
        {
            int row = t >> 2, kb = (t & 3) * 4;
            float4 xv = make_float4(0.f, 0.f, 0.f, 0.f);
            if (k0 + kb < XS) xv = *(const float4*)&X[(size_t)(r0 + row) * XS + k0 + kb];
            float vv[4] = {xv.x, xv.y, xv.z, xv.w};
#pragma unroll
            for (int u = 0; u < 4; ++u) {
                int k = k0 + kb + u;
                float v = 0.f;
                if (k < K) {
                    v = vv[u];
                    if (ACT) { float z = fmaf(v, scale[k], shift[k]); v = fmaxf(z, 0.2f * z); }
                }
                Xs[kb + u][row] = v;
            }
            int kw = t >> 4, ow = (t & 15) * 4;
            float4 wv = make_float4(0.f, 0.f, 0.f, 0.f);
            if (k0 + kw < K) wv = *(const float4*)&W[(size_t)(k0 + kw) * OC + o0 + ow];
            *(float4*)&Ws[kw][ow] = wv;
        }
        __syncthreads();
#pragma unroll
        for (int k = 0; k < 16; ++k) {
            float4 a = *(const float4*)&Xs[k][ty * 4];
            float4 bb = *(const float4*)&Ws[k][tx * 4];
            float av[4] = {a.x, a.y, a.z, a.w};
            float bvv[4] = {bb.x, bb.y, bb.z, bb.w};
#pragma unroll
            for (int i = 0; i < 4; ++i)
#pragma unroll
                for (int j = 0; j < 4; ++j)
                    acc[i][j] = fmaf(av[i], bvv[j], acc[i][j]);
        }
    }
#pragma unroll
    for (int i = 0; i < 4; ++i) {
        int r = r0 + ty * 4 + i;
        float4 o4;
        float* po = (float*)&o4;
#pragma unroll
        for (int j = 0; j < 4; ++j) {
            float v = acc[i][j];
            if (BIAS) v += bias[(size_t)(r >> 10) * OC + o0 + tx * 4 + j];
            po[j] = v;
        }
        *(float4*)&Y[(size_t)r * OC + o0 + tx * 4] = o4;
    }
}

// ---------- gather neighbors, max over k, per-block BN partials (deterministic).
template<int O>
__global__ __launch_bounds__(256) void k_gather(const float* __restrict__ Z,
    const int* __restrict__ idxb, float* __restrict__ xo,
    float* __restrict__ part_s, float* __restrict__ part_q)
{
    constexpr int OL = O / 64;
    __shared__ float rs[4][O], rq[4][O];
    int b = blockIdx.y, nt = blockIdx.x;
    int t = threadIdx.x, lane = t & 63, w = t >> 6;
    float ps[OL] = {}, pq[OL] = {};
    for (int i = 0; i < 4; ++i) {
        int n = nt * 16 + w * 4 + i;
        size_t r = (size_t)b * NN + n;
        float zd[OL], ym[OL];
#pragma unroll
        for (int j = 0; j < OL; ++j) {
            int o = lane + j * 64;
            zd[j] = Z[r * (2 * O) + O + o] - Z[r * (2 * O) + o];
            ym[j] = -3.4e38f;
        }
        int midx[KNN];
        {
            const int4* ip = (const int4*)&idxb[r * KNN];
#pragma unroll
            for (int q = 0; q < 5; ++q) {
                int4 t4 = ip[q];
                midx[4 * q + 0] = t4.x; midx[4 * q + 1] = t4.y;
                midx[4 * q + 2] = t4.z; midx[4 * q + 3] = t4.w;
            }
        }
#pragma unroll
        for (int k = 0; k < KNN; ++k) {
            size_t rm = (size_t)b * NN + midx[k];
#pragma unroll
            for (int j = 0; j < OL; ++j) {
                float y = Z[rm * (2 * O) + lane + j * 64] + zd[j];
                ym[j] = fmaxf(ym[j], y);
                ps[j] += y; pq[j] = fmaf(y, y, pq[j]);
            }
        }
#pragma unroll
        for (int j = 0; j < OL; ++j) xo[r * O + lane + j * 64] = ym[j];
    }
#pragma unroll
    for (int j = 0; j < OL; ++j) { rs[w][lane + j * 64] = ps[j]; rq[w][lane + j * 64] = pq[j]; }
    __syncthreads();
    if (w == 0) {
        int blk = blockIdx.y * 64 + blockIdx.x;  // 0..2047, fixed slot per block
#pragma unroll
        for (int j = 0; j < OL; ++j) {
            int o = lane + j * 64;
            part_s[(size_t)o * 2048 + blk] = rs[0][o] + rs[1][o] + rs[2][o] + rs[3][o];
            part_q[(size_t)o * 2048 + blk] = rq[0][o] + rq[1][o] + rq[2][o] + rq[3][o];
        }
    }
}

// ---------- deterministic BN finalize from fixed-slot partials (2048 slots)
__global__ void k_bnfin2(const float* __restrict__ part_s, const float* __restrict__ part_q,
                         const float* __restrict__ g, const float* __restrict__ bb,
                         float* __restrict__ scale, float* __restrict__ shift,
                         int OC, float invM, float eps)
{
    int o = blockIdx.x * blockDim.x + threadIdx.x;
    if (o >= OC) return;
    const float* ps = part_s + (size_t)o * 2048;
    const float* pq = part_q + (size_t)o * 2048;
    float s0 = 0.f, s1 = 0.f, s2 = 0.f, s3 = 0.f;
    float q0 = 0.f, q1 = 0.f, q2 = 0.f, q3 = 0.f;
    for (int i = 0; i < 2048; i += 4) {
        s0 += ps[i]; s1 += ps[i + 1]; s2 += ps[i + 2]; s3 += ps[i + 3];
        q0 += pq[i]; q1 += pq[i + 1]; q2 += pq[i + 2]; q3 += pq[i + 3];
    }
    float s = (s0 + s1) + (s2 + s3);
    float q = (q0 + q1) + (q2 + q3);
    float mu = s * invM;
    float var = q * invM - mu * mu;
    float sc = g[o] * rsqrtf(var + eps);
    scale[o] = sc; shift[o] = bb[o] - mu * sc;
}

// ---------- conv-chain BN finalize from fixed-slot partials (128 slots)
__global__ void k_bnfin3(const float* __restrict__ part_s, const float* __restrict__ part_q,
                         const float* __restrict__ g, const float* __restrict__ bb,
                         float* __restrict__ scale, float* __restrict__ shift,
                         int OC, float invM, float eps)
{
    int o = blockIdx.x * blockDim.x + threadIdx.x;
    if (o >= OC) return;
    const float* ps = part_s + (size_t)o * 128;
    const float* pq = part_q + (size_t)o * 128;
    float s0 = 0.f, s1 = 0.f, s2 = 0.f, s3 = 0.f;
    float q0 = 0.f, q1 = 0.f, q2 = 0.f, q3 = 0.f;
    for (int i = 0; i < 128; i += 4) {
        s0 += ps[i]; s1 += ps[i + 1]; s2 += ps[i + 2]; s3 += ps[i + 3];
        q0 += pq[i]; q1 += pq[i + 1]; q2 += pq[i + 2]; q3 += pq[i + 3];
    }
    float s = (s0 + s1) + (s2 + s3);
    float q = (q0 + q1) + (q2 + q3);
    float mu = s * invM;
    float var = q * invM - mu * mu;
    float sc = g[o] * rsqrtf(var + eps);
    scale[o] = sc; shift[o] = bb[o] - mu * sc;
}

// ---------- elementwise BN apply + lrelu (in place)
__global__ void k_bnapply(float* __restrict__ x, const float* __restrict__ scale,
                          const float* __restrict__ shift, int total, int O)
{
    int i = blockIdx.x * 256 + threadIdx.x;
    if (i >= total) return;
    int o = i & (O - 1);
    x[i] = lrelu(fmaf(x[i], scale[o], shift[o]));
}

// ---------- BN apply + lrelu + row-norm for O=64 tensors (xt1/xt2), float4.
__global__ __launch_bounds__(256) void k_bnapply_rn(float* __restrict__ x,
    const float* __restrict__ scale, const float* __restrict__ shift,
    float* __restrict__ xx)
{
    __shared__ float red[16][17];
    int t = threadIdx.x;
    int i4 = blockIdx.x * 256 + t;
    int q = t & 15, lrow = t >> 4;
    float4 v = ((float4*)x)[i4];
    int o = q * 4;
    v.x = lrelu(fmaf(v.x, scale[o + 0], shift[o + 0]));
    v.y = lrelu(fmaf(v.y, scale[o + 1], shift[o + 1]));
    v.z = lrelu(fmaf(v.z, scale[o + 2], shift[o + 2]));
    v.w = lrelu(fmaf(v.w, scale[o + 3], shift[o + 3]));
    ((float4*)x)[i4] = v;
    float part = fmaf(v.w, v.w, fmaf(v.z, v.z, fmaf(v.y, v.y, v.x * v.x)));
    red[lrow][q] = part;
    __syncthreads();
    if (t < 16) {
        float s = 0.f;
#pragma unroll
        for (int j = 0; j < 16; ++j) s += red[t][j];
        xx[blockIdx.x * 16 + t] = s;
    }
}

// ---------- concat x1|x2|x3 -> fcat (B*N, 256)
__global__ void k_concat(const float* __restrict__ x1, const float* __restrict__ x2,
                         const float* __restrict__ x3, float* __restrict__ f)
{
    int i = blockIdx.x * 256 + threadIdx.x;
    if (i >= RTOT * 256) return;
    int r = i >> 8, c = i & 255;
    float v;
    if (c < 64) v = x1[(size_t)r * 64 + c];
    else if (c < 128) v = x2[(size_t)r * 64 + c - 64];
    else v = x3[(size_t)r * 128 + c - 128];
    f[(size_t)i] = v;
}

// ---------- LayerNorm stats per b over (N,40) of h (stride 64)
__global__ __launch_bounds__(256) void k_lnstats(const float* __restrict__ h, float* __restrict__ st)
{
    __shared__ float rsm[256], rqm[256];
    int b = blockIdx.x, t = threadIdx.x;
    float s = 0.f, q = 0.f;
    for (int i = t; i < 40960; i += 256) {
        int n = i / 40, o = i - n * 40;
        float v = h[((size_t)b * NN + n) * 64 + o];
        s += v; q = fmaf(v, v, q);
    }
    rsm[t] = s; rqm[t] = q; __syncthreads();
    for (int off = 128; off; off >>= 1) {
        if (t < off) { rsm[t] += rsm[t + off]; rqm[t] += rqm[t + off]; }
        __syncthreads();
    }
    if (t == 0) {
        float mu = rsm[0] / 40960.f;
        float var = rqm[0] / 40960.f - mu * mu;
        st[2 * b] = mu; st[2 * b + 1] = rsqrtf(var + 1e-6f);
    }
}

// ---------- LayerNorm apply + relu (in place on h -> encoder)
__global__ void k_lnapply(float* __restrict__ h, const float* __restrict__ lnw,
                          const float* __restrict__ lnb, const float* __restrict__ st)
{
    int i = blockIdx.x * 256 + threadIdx.x;
    if (i >= NB * NN * 40) return;
    int b = i / 40960, rem = i - b * 40960, n = rem / 40, o = rem - n * 40;
    float mu = st[2 * b], rstd = st[2 * b + 1];
    size_t a = ((size_t)b * NN + n) * 64 + o;
    float v = fmaf((h[a] - mu) * rstd, lnw[n * 40 + o], lnb[n * 40 + o]);
    h[a] = fmaxf(v, 0.f);
}

// ---------- u_hat fused with s1 = sum_p u. U stored bf16 (RNE); s1 partials stay f32.
__global__ __launch_bounds__(64) void k_uhat(const float* __restrict__ enc,
    const float* __restrict__ caps, unsigned short* __restrict__ U, float* __restrict__ pbu)
{
    __shared__ float clt[40 * 68];
    int pc = blockIdx.x, l = blockIdx.y;
    int lane = threadIdx.x;
    int vg = lane & 7, bg = lane >> 3;
    int v0 = vg * 8, b0 = bg * 4;
    float spart[4][8] = {};
#pragma unroll 1
    for (int pi = 0; pi < 16; ++pi) {
        int p = pc * 16 + pi;
        const float4* cp4 = (const float4*)(caps + ((size_t)l * NN + p) * 2560);
#pragma unroll
        for (int k = 0; k < 10; ++k) {
            int i4 = lane + k * 64;        // 0..639
            float4 cv = cp4[i4];
            int e0 = i4 * 4;
            int v = e0 / 40;
            int d0 = e0 - v * 40;
            clt[(d0 + 0) * 68 + v] = cv.x;
            clt[(d0 + 1) * 68 + v] = cv.y;
            clt[(d0 + 2) * 68 + v] = cv.z;
            clt[(d0 + 3) * 68 + v] = cv.w;
        }
        float acc[4][8] = {};
#pragma unroll
        for (int d4 = 0; d4 < 10; ++d4) {
            float4 e4[4];
#pragma unroll
            for (int i = 0; i < 4; ++i)
                e4[i] = *(const float4*)&enc[((size_t)(b0 + i) * NN + p) * 64 + d4 * 4];
#pragma unroll
            for (int dd = 0; dd < 4; ++dd) {
                int d = d4 * 4 + dd;
                float4 c0 = *(const float4*)&clt[d * 68 + v0];
                float4 c1 = *(const float4*)&clt[d * 68 + v0 + 4];
                float cv[8] = {c0.x, c0.y, c0.z, c0.w, c1.x, c1.y, c1.z, c1.w};
#pragma unroll
                for (int i = 0; i < 4; ++i) {
                    float e = ((const float*)&e4[i])[dd];
#pragma unroll
                    for (int j = 0; j < 8; ++j)
                        acc[i][j] = fmaf(e, cv[j], acc[i][j]);
                }
            }
        }
#pragma unroll
        for (int i = 0; i < 4; ++i) {
            uint4 pk;
            pk.x = bfpack(acc[i][0], acc[i][1]);
            pk.y = bfpack(acc[i][2], acc[i][3]);
            pk.z = bfpack(acc[i][4], acc[i][5]);
            pk.w = bfpack(acc[i][6], acc[i][7]);
            *(uint4*)&U[((size_t)(b0 + i) * NN + p) * 2560 + l * 64 + v0] = pk;
#pragma unroll
            for (int j = 0; j < 8; ++j) spart[i][j] += acc[i][j];
        }
    }
    float* pb = pbu + (size_t)pc * 81920;
#pragma unroll
    for (int i = 0; i < 4; ++i) {
        float4 s0 = make_float4(spart[i][0], spart[i][1], spart[i][2], spart[i][3]);
        float4 s1 = make_float4(spart[i][4], spart[i][5], spart[i][6], spart[i][7]);
        float* dst = &pb[(size_t)(b0 + i) * 2560 + l * 64 + v0];
        *(float4*)dst = s0;
        *(float4*)(dst + 4) = s1;
    }
}

// ---------- routing pass over bf16 U (uint2 = 4 bf16 per lane per it; half the
// stream bytes and half the u-register state vs f32). Deterministic.
template<int MODE>
__global__ __launch_bounds__(256, 4) void k_route(const unsigned short* __restrict__ U,
    const float* __restrict__ vprev, const float* __restrict__ bin,
    float* __restrict__ bout, float* __restrict__ pbuf)
{
    __shared__ float vl[2560];
    __shared__ float red[4][1280];
    int b = blockIdx.x, pc = blockIdx.y;
    int t = threadIdx.x, lane = t & 63, w = t >> 6;
    for (int i = t; i < 2560; i += 256) vl[i] = vprev[(size_t)b * 2560 + i];
    __syncthreads();
    float4 acc[10];
#pragma unroll
    for (int it = 0; it < 10; ++it) acc[it] = make_float4(0.f, 0.f, 0.f, 0.f);
    int lgrp = lane >> 4;
#pragma unroll 1
    for (int pi = 0; pi < 8; ++pi) {
        int p = pc * 32 + w * 8 + pi;
        const uint2* up2 = (const uint2*)(U + ((size_t)b * NN + p) * 2560);
        uint2 ur[10];
#pragma unroll
        for (int it = 0; it < 10; ++it) ur[it] = up2[it * 64 + lane];
        float pd[10];
#pragma unroll
        for (int it = 0; it < 10; ++it) {
            float4 vv = *(const float4*)&vl[it * 256 + lane * 4];
            float s = bflo(ur[it].x) * vv.x;
            s = fmaf(bfhi(ur[it].x), vv.y, s);
            s = fmaf(bflo(ur[it].y), vv.z, s);
            s = fmaf(bfhi(ur[it].y), vv.w, s);
            s += __shfl_xor(s, 1, 64);
            s += __shfl_xor(s, 2, 64);
            s += __shfl_xor(s, 4, 64);
            s += __shfl_xor(s, 8, 64);
            pd[it] = s;
        }
        if (MODE == 1) {
            if ((lane & 15) == 0) {
#pragma unroll
                for (int it = 0; it < 10; ++it)
                    bout[((size_t)b * 40 + it * 4 + lgrp) * NN + p] = pd[it];
            }
        } else {
#pragma unroll
            for (int it = 0; it < 10; ++it)
                pd[it] += bin[((size_t)b * 40 + it * 4 + lgrp) * NN + p];
        }
        float mx = -3.4e38f;
#pragma unroll
        for (int it = 0; it < 10; ++it) {
            float m = pd[it];
            m = fmaxf(m, __shfl_xor(m, 16, 64));
            m = fmaxf(m, __shfl_xor(m, 32, 64));
            mx = fmaxf(mx, m);
        }
        float eo[10]; float se = 0.f;
#pragma unroll
        for (int it = 0; it < 10; ++it) {
            float e = expf(pd[it] - mx);
            eo[it] = e;
            float sg = e;
            sg += __shfl_xor(sg, 16, 64);
            sg += __shfl_xor(sg, 32, 64);
            se += sg;
        }
        float inv = 1.f / se;
#pragma unroll
        for (int it = 0; it < 10; ++it) {
            float wgt = eo[it] * inv;
            acc[it].x = fmaf(wgt, bflo(ur[it].x), acc[it].x);
            acc[it].y = fmaf(wgt, bfhi(ur[it].x), acc[it].y);
            acc[it].z = fmaf(wgt, bflo(ur[it].y), acc[it].z);
            acc[it].w = fmaf(wgt, bfhi(ur[it].y), acc[it].w);
        }
    }
    float* pb = pbuf + ((size_t)pc * NB + b) * 2560;
#pragma unroll 1
    for (int h = 0; h < 2; ++h) {
        __syncthreads();
#pragma unroll
        for (int it = 0; it < 5; ++it)
            *(float4*)&red[w][it * 256 + lane * 4] = acc[h * 5 + it];
        __syncthreads();
        if (w == 0) {
#pragma unroll
            for (int it = 0; it < 5; ++it) {
                int idx = it * 256 + lane * 4;
                float4 a0 = *(const float4*)&red[0][idx];
                float4 a1 = *(const float4*)&red[1][idx];
                float4 a2 = *(const float4*)&red[2][idx];
                float4 a3 = *(const float4*)&red[3][idx];
                float4 o = make_float4((a0.x + a1.x) + (a2.x + a3.x),
                                       (a0.y + a1.y) + (a2.y + a3.y),
                                       (a0.z + a1.z) + (a2.z + a3.z),
                                       (a0.w + a1.w) + (a2.w + a3.w));
                *(float4*)&pb[h * 1280 + idx] = o;
            }
        }
    }
}

// ---------- fused: reduce partials over NCH chunks + squash -> vb. Deterministic.
template<int NCH>
__global__ __launch_bounds__(256) void k_sredsq(const float* __restrict__ pbuf,
    float* __restrict__ vout, float premul)
{
    __shared__ float red[16][17];
    __shared__ float fac[16];
    int t = threadIdx.x;
    int i4 = blockIdx.x * 256 + t;
    int q = t & 15, lrow = t >> 4;
    const float4* pb4 = (const float4*)pbuf;
    float4 s = make_float4(0.f, 0.f, 0.f, 0.f);
#pragma unroll 4
    for (int pc = 0; pc < NCH; ++pc) {
        float4 v = pb4[(size_t)pc * (NB * 640) + i4];
        s.x += v.x; s.y += v.y; s.z += v.z; s.w += v.w;
    }
    s.x *= premul; s.y *= premul; s.z *= premul; s.w *= premul;
    float part = fmaf(s.w, s.w, fmaf(s.z, s.z, fmaf(s.y, s.y, s.x * s.x)));
    red[lrow][q] = part;
    __syncthreads();
    if (t < 16) {
        float sn = 0.f;
#pragma unroll
        for (int j = 0; j < 16; ++j) sn += red[t][j];
        fac[t] = sn / ((1.f + sn) * sqrtf(sn));
    }
    __syncthreads();
    float f = fac[lrow];
    ((float4*)vout)[i4] = make_float4(s.x * f, s.y * f, s.z * f, s.w * f);
}

// ---------- emb = enc @ latent, max over v
__global__ __launch_bounds__(256) void k_emb(const float* __restrict__ enc,
    const float* __restrict__ lat, float* __restrict__ embm)
{
    __shared__ float latl[2560];
    int b = blockIdx.x, pt = blockIdx.y;
    int t = threadIdx.x, lane = t & 63, w = t >> 6;
    for (int i = t; i < 2560; i += 256) latl[i] = lat[(size_t)b * 2560 + i];
    __syncthreads();
    for (int i = 0; i < 32; ++i) {
        int p = pt * 128 + w * 32 + i;
        const float* ep = enc + ((size_t)b * NN + p) * 64;
        float acc = 0.f;
#pragma unroll
        for (int d = 0; d < 40; ++d) acc = fmaf(ep[d], latl[d * 64 + lane], acc);
        float mx = acc;
#pragma unroll
        for (int s = 32; s; s >>= 1) mx = fmaxf(mx, __shfl_xor(mx, s, 64));
        if (lane == 0) embm[(size_t)b * NN + p] = mx;
    }
}

// ---------- base2 with integrated lab
__global__ __launch_bounds__(256) void k_base2(const float* __restrict__ em,
    const float* __restrict__ lin, const float* __restrict__ cw1,
    const float* __restrict__ cg1, const float* __restrict__ cb1,
    const float* __restrict__ cw2, float* __restrict__ base)
{
    __shared__ float eml[1024];
    __shared__ float lbl[64];
    int b = blockIdx.x, t = threadIdx.x;
    for (int i = t; i < 1024; i += 256) eml[i] = em[(size_t)b * NN + i];
    if (t < 64) {
        int o = t;
        float ys[32]; float s = 0.f, q = 0.f;
#pragma unroll
        for (int bb = 0; bb < 32; ++bb) {
            float y = 0.f;
#pragma unroll
            for (int c = 0; c < 16; ++c) y = fmaf(lin[bb * 16 + c], cw1[o * 16 + c], y);
            ys[bb] = y; s += y; q = fmaf(y, y, q);
        }
        float mu = s / 32.f, var = q / 32.f - mu * mu;
        float sc = cg1[o] * rsqrtf(var + 1e-5f);
        float sh = cb1[o] - mu * sc;
        lbl[o] = lrelu(fmaf(ys[b], sc, sh));
    }
    __syncthreads();
    const float* wr = cw2 + (size_t)t * 1128;
    float acc = 0.f;
    for (int c = 0; c < 1024; ++c) acc = fmaf(wr[c], eml[c], acc);
#pragma unroll
    for (int c = 0; c < 64; ++c) acc = fmaf(wr[1024 + c], lbl[c], acc);
    base[b * 256 + t] = acc;
}

// ---------- column stats over rows, fixed-slot partials (deterministic)
__global__ __launch_bounds__(256) void k_colstats2(const float* __restrict__ Y,
    float* __restrict__ part_s, float* __restrict__ part_q, int OC)
{
    __shared__ float rs[4][64], rq[4][64];
    int chunk = blockIdx.x, o0 = blockIdx.y * 64;
    int t = threadIdx.x, lane = t & 63, w = t >> 6;
    int o = o0 + lane;
    float s = 0.f, q = 0.f;
    for (int j = 0; j < 64; ++j) {
        int r = chunk * 256 + w * 64 + j;
        float v = Y[(size_t)r * OC + o];
        s += v; q = fmaf(v, v, q);
    }
    rs[w][lane] = s; rq[w][lane] = q;
    __syncthreads();
    if (w == 0) {
        part_s[(size_t)o * 128 + chunk] = rs[0][lane] + rs[1][lane] + rs[2][lane] + rs[3][lane];
        part_q[(size_t)o * 128 + chunk] = rq[0][lane] + rq[1][lane] + rq[2][lane] + rq[3][lane];
    }
}

// ---------- final: BN+lrelu+transpose to out (B,50,N)
__global__ void k_out(const float* __restrict__ Y, const float* __restrict__ scale,
                      const float* __restrict__ shift, float* __restrict__ out)
{
    int i = blockIdx.x * 256 + threadIdx.x;
    if (i >= NB * 50 * NN) return;
    int n = i & 1023, rest = i >> 10;
    int o = rest % 50, b = rest / 50;
    float y = Y[((size_t)b * NN + n) * 64 + o];
    out[i] = lrelu(fmaf(y, scale[o], shift[o]));
}

extern "C" void kernel_launch(void* const* d_in, const int* in_sizes, int n_in,
                              void* d_out, int out_size, void* d_ws, size_t ws_size,
                              hipStream_t stream)
{
    const float* data = (const float*)d_in[0];
    const float* lin  = (const float*)d_in[1];
    const float* dw1  = (const float*)d_in[2];
    const float* dg1  = (const float*)d_in[3];
    const float* db1  = (const float*)d_in[4];
    const float* dw2  = (const float*)d_in[5];
    const float* dg2  = (const float*)d_in[6];
    const float* db2  = (const float*)d_in[7];
    const float* dw3  = (const float*)d_in[8];
    const float* dg3  = (const float*)d_in[9];
    const float* db3  = (const float*)d_in[10];
    const float* lw   = (const float*)d_in[11];
    const float* lnw  = (const float*)d_in[12];
    const float* lnb  = (const float*)d_in[13];
    const float* caps = (const float*)d_in[14];
    const float* cw1  = (const float*)d_in[15];
    const float* cg1  = (const float*)d_in[16];
    const float* cb1  = (const float*)d_in[17];
    const float* cw2  = (const float*)d_in[18];
    const float* cg2  = (const float*)d_in[19];
    const float* cb2  = (const float*)d_in[20];
    const float* cw3  = (const float*)d_in[21];
    const float* cw4  = (const float*)d_in[22];
    const float* cg4  = (const float*)d_in[23];
    const float* cb4  = (const float*)d_in[24];
    const float* cw5  = (const float*)d_in[25];
    const float* cg5  = (const float*)d_in[26];
    const float* cb5  = (const float*)d_in[27];
    float* out = (float*)d_out;
    float* ws = (float*)d_ws;

    float* big  = ws + O_BIG;
    float* xt0  = ws + O_XT0;
    float* xt1  = ws + O_XT1;
    float* xt2  = ws + O_XT2;
    float* xt3  = ws + O_XT3;
    float* xxp  = ws + O_XX;
    int*   idxb = (int*)(ws + O_IDX);
    float* wc1  = ws + O_WC1;
    float* wc2  = ws + O_WC2;
    float* wc3  = ws + O_WC3;
    float* lwt  = ws + O_LWT;
    float* c2t  = ws + O_C2T;
    float* c3t  = ws + O_C3T;
    float* c4t  = ws + O_C4T;
    float* c5t  = ws + O_C5T;
    float* hbuf = ws + O_H;
    float* lnst = ws + O_LNST;
    float* scl  = ws + O_SCL;
    float* shf  = ws + O_SHF;
    float* vb   = ws + O_VB;
    float* bij  = ws + O_BIJ;
    float* embm = ws + O_EMB;
    float* basep= ws + O_BASE;
    float* psP  = ws + O_PS;
    float* pqP  = ws + O_PQ;
    float* pbuf = ws + O_PB;
    float* pbu  = ws + O_PBU;
    float* Dbuf = big;              // distances, Z, fcat, ybufs alias big
    float* Z    = big;
    unsigned short* U = (unsigned short*)big;   // bf16 u_hat (168 MB; lifetime disjoint)
    float* yb1  = big;
    float* yb2  = big + 8388608;

    // ---- weight prep (single kernel) + data transpose w/ fused norm
    k_wtall<<<618, 256, 0, stream>>>(dw1, dw2, dw3, lw, cw2, cw3, cw4, cw5,
                                     wc1, wc2, wc3, lwt, c2t, c3t, c4t, c5t);
    k_data_t<<<128, 256, 0, stream>>>(data, xt0, xxp);

    // ---- stage 1 (C=3 -> O=64)
    k_dist<4><<<dim3(16, 16, 32), 256, 0, stream>>>(xt0, xxp, Dbuf);
    k_sel<<<8192, 256, 0, stream>>>(Dbuf, idxb);
    k_gemm<false, false><<<dim3(512, 2), 256, 0, stream>>>(xt0, wc1, Z, 3, 128, 4, nullptr, nullptr, nullptr);
    k_gather<64><<<dim3(64, 32), 256, 0, stream>>>(Z, idxb, xt1, psP, pqP);
    k_bnfin2<<<1, 64, 0, stream>>>(psP, pqP, dg1, db1, scl, shf, 64, 1.f / 655360.f, 1e-5f);
    k_bnapply_rn<<<2048, 256, 0, stream>>>(xt1, scl, shf, xxp);

    // ---- stage 2 (C=64 -> O=64)
    k_dist<64><<<dim3(16, 16, 32), 256, 0, stream>>>(xt1, xxp, Dbuf);
    k_sel<<<8192, 256, 0, stream>>>(Dbuf, idxb);
    k_gemm<false, false><<<dim3(512, 2), 256, 0, stream>>>(xt1, wc2, Z, 64, 128, 64, nullptr, nullptr, nullptr);
    k_gather<64><<<dim3(64, 32), 256, 0, stream>>>(Z, idxb, xt2, psP, pqP);
    k_bnfin2<<<1, 64, 0, stream>>>(psP, pqP, dg2, db2, scl, shf, 64, 1.f / 655360.f, 1e-5f);
    k_bnapply_rn<<<2048, 256, 0, stream>>>(xt2, scl, shf, xxp);

    // ---- stage 3 (C=64 -> O=128)
    k_dist<64><<<dim3(16, 16, 32), 256, 0, stream>>>(xt2, xxp, Dbuf);
    k_sel<<<8192, 256, 0, stream>>>(Dbuf, idxb);
    k_gemm<false, false><<<dim3(512, 4), 256, 0, stream>>>(xt2, wc3, Z, 64, 256, 64, nullptr, nullptr, nullptr);
    k_gather<128><<<dim3(64, 32), 256, 0, stream>>>(Z, idxb, xt3, psP, pqP);
    k_bnfin2<<<1, 128, 0, stream>>>(psP, pqP, dg3, db3, scl, shf, 128, 1.f / 655360.f, 1e-5f);
    k_bnapply<<<16384, 256, 0, stream>>>(xt3, scl, shf, RTOT * 128, 128);

    // ---- feat concat, linear, LayerNorm (-> encoder in hbuf)
    k_concat<<<32768, 256, 0, stream>>>(xt1, xt2, xt3, big);
    k_gemm<false, false><<<dim3(512, 1), 256, 0, stream>>>(big, lwt, hbuf, 256, 64, 256, nullptr, nullptr, nullptr);
    k_lnstats<<<32, 256, 0, stream>>>(hbuf, lnst);
    k_lnapply<<<5120, 256, 0, stream>>>(hbuf, lnw, lnb, lnst);

    // ---- capsules (xt1..xt3 now dead -> pbu/pbuf alias them; U bf16 aliases big)
    k_uhat<<<dim3(64, 40), 64, 0, stream>>>(hbuf, caps, U, pbu);
    k_sredsq<64><<<80, 256, 0, stream>>>(pbu, vb, 1.f / 40.f);
    k_route<1><<<dim3(32, 32), 256, 0, stream>>>(U, vb, nullptr, bij, pbuf);
    k_sredsq<32><<<80, 256, 0, stream>>>(pbuf, vb, 1.f);
    k_route<2><<<dim3(32, 32), 256, 0, stream>>>(U, vb, bij, nullptr, pbuf);
    k_sredsq<32><<<80, 256, 0, stream>>>(pbuf, vb, 1.f);

    // ---- emb, base2 (lab integrated)
    k_emb<<<dim3(32, 8), 256, 0, stream>>>(hbuf, vb, embm);
    k_base2<<<32, 256, 0, stream>>>(embm, lin, cw1, cg1, cb1, cw2, basep);

    // ---- conv chain (deterministic fixed-slot BN partials)
    k_gemm<false, true><<<dim3(512, 4), 256, 0, stream>>>(hbuf, c2t, yb1, 40, 256, 64, nullptr, nullptr, basep);
    k_colstats2<<<dim3(128, 4), 256, 0, stream>>>(yb1, psP, pqP, 256);
    k_bnfin3<<<1, 256, 0, stream>>>(psP, pqP, cg2, cb2, scl, shf, 256, 1.f / 32768.f, 1e-5f);

    k_gemm<true, false><<<dim3(512, 4), 256, 0, stream>>>(yb1, c3t, yb2, 256, 256, 256, scl, shf, nullptr);
    k_colstats2<<<dim3(128, 4), 256, 0, stream>>>(yb2, psP, pqP, 256);
    k_bnfin3<<<1, 256, 0, stream>>>(psP, pqP, cg2, cb2, scl, shf, 256, 1.f / 32768.f, 1e-5f);

    k_gemm<true, false><<<dim3(512, 2), 256, 0, stream>>>(yb2, c4t, yb1, 256, 128, 256, scl, shf, nullptr);
    k_colstats2<<<dim3(128, 2), 256, 0, stream>>>(yb1, psP, pqP, 128);
    k_bnfin3<<<1, 256, 0, stream>>>(psP, pqP, cg4, cb4, scl, shf, 128, 1.f / 32768.f, 1e-5f);

    k_gemm<true, false><<<dim3(512, 1), 256, 0, stream>>>(yb1, c5t, yb2, 128, 64, 128, scl, shf, nullptr);
    k_colstats2<<<dim3(128, 1), 256, 0, stream>>>(yb2, psP, pqP, 64);
    k_bnfin3<<<1, 256, 0, stream>>>(psP, pqP, cg5, cb5, scl, shf, 50, 1.f / 32768.f, 1e-5f);

    k_out<<<6400, 256, 0, stream>>>(yb2, scl, shf, out);
}